// Round 11
// baseline (1772.755 us; speedup 1.0000x reference)
//
#include <hip/hip_runtime.h>

// LSTM decoder B=2048, Z=64, A=8, H=512, T=64.
// Round 11: persistent cooperative kernel, fence-free flag sync (r10-proven),
// minus r10's measured costs: A (h) loaded straight to registers via relaxed
// agent-scope atomics (no LDS A-tile -> no AWRITE bank conflicts), B chunks
// 0/1 prefetched cross-step during the cell phase, counted vmcnt everywhere.
// Clusters are XCD-local (bid&7 == bt&7). Fallback: r9 multi-launch (926us).

#define HID   512
#define TSTEP 64
#define KCAT  576

typedef unsigned long long u64;
typedef __attribute__((ext_vector_type(8))) short bf16x8;
typedef __attribute__((ext_vector_type(4))) float f32x4;
struct U64x2 { u64 lo, hi; };

__device__ inline unsigned short f2bf(float f) {
  unsigned int u = __builtin_bit_cast(unsigned int, f);
  unsigned int r = (u + 0x7fffu + ((u >> 16) & 1u)) >> 16;
  return (unsigned short)r;
}
__device__ inline float sigm(float x) { return 1.0f / (1.0f + __expf(-x)); }
__device__ inline float tanh_f(float x) { return 1.0f - 2.0f / (__expf(2.0f * x) + 1.0f); }
__device__ inline bf16x8 mkfrag(u64 lo, u64 hi) {
  U64x2 t{lo, hi};
  return __builtin_bit_cast(bf16x8, t);
}

__device__ inline void gl16(const unsigned short* g, unsigned short* l) {
  __builtin_amdgcn_global_load_lds(
      (const __attribute__((address_space(1))) unsigned int*)g,
      (__attribute__((address_space(3))) unsigned int*)l, 16, 0, 0);
}

#define ATOMLD(PTR) __hip_atomic_load((PTR), __ATOMIC_RELAXED, __HIP_MEMORY_SCOPE_AGENT)
#define ATOMST(PTR, V) __hip_atomic_store((PTR), (V), __ATOMIC_RELAXED, __HIP_MEMORY_SCOPE_AGENT)

// ---- merged prep: wcat (bf16 [W_hh|W_ih_z]), zbf, bias ----
__global__ void k_prep(const float* __restrict__ z, const float* __restrict__ wih,
                       const float* __restrict__ whh, const float* __restrict__ bih,
                       const float* __restrict__ bhh,
                       unsigned short* __restrict__ wcat, unsigned short* __restrict__ zbf,
                       float* __restrict__ bias) {
  int c = blockIdx.x * 256 + threadIdx.x;
  if (c < 147456) {
    int n = c / 72, kc = (c % 72) * 8;
    unsigned short u[8];
#pragma unroll
    for (int e = 0; e < 8; ++e) {
      int k = kc + e;
      float v = (k < 512) ? whh[(size_t)n * 512 + k] : wih[(size_t)n * 72 + 8 + (k - 512)];
      u[e] = f2bf(v);
    }
    *(bf16x8*)&wcat[(size_t)n * KCAT + kc] = *(bf16x8*)u;
  } else if (c < 163840) {
    int i = c - 147456;
    int row = i >> 3, kc = (i & 7) * 8;
    unsigned short u[8];
#pragma unroll
    for (int e = 0; e < 8; ++e) u[e] = f2bf(z[(size_t)row * 64 + kc + e]);
    *(bf16x8*)&zbf[(size_t)row * 64 + kc] = *(bf16x8*)u;
  } else if (c < 165888) {
    int n = c - 163840;
    bias[n] = bih[n] + bhh[n];
  }
}

__global__ void k_zero(int* __restrict__ flags) {
  int g = blockIdx.x * 256 + threadIdx.x;
  if (g < TSTEP * 32) flags[g] = 0;
}

struct P {
  const unsigned short *wcat, *zbf;
  const float *bias, *wout, *bout;
  unsigned short *h0, *h1;
  float* out;
  int* flags;
};

__global__ __launch_bounds__(256, 2) void k_persist(P p) {
  __shared__ unsigned short Bb[2][128 * 64];   // 32 KB: W chunk double-buffer
  __shared__ unsigned short wo[16 * 512];      // 16 KB: W_out bf16 swizzled (nt==0)
  __shared__ unsigned short hO[64 * 40];       //  5 KB: h staging for stores

  const int bid = blockIdx.x;
  const int nt = bid >> 5, bt = bid & 31;      // bid&7 == bt&7 -> XCD-local cluster
  const int tid = threadIdx.x;
  const int lane = tid & 63;
  const int wv = tid >> 6;
  const int mq = wv >> 1, nh = wv & 1;
  const int cl = lane & 15, q8 = lane >> 4;
  const int b0 = bt * 64, j0 = nt * 32;

  // ---- B staging (verified r9/r10 pattern) ----
  const int rS = tid >> 3;
  const int xS = ((tid & 7) ^ (rS & 7)) * 8;
  const unsigned short* srcB[4];
#pragma unroll
  for (int k = 0; k < 4; ++k) {
    int rB = k * 32 + rS;
    int n = (rB >> 5) * HID + j0 + (rB & 31);
    srcB[k] = p.wcat + (size_t)n * KCAT + xS;
  }
#define STAGEB(BUF, CHUNK) { _Pragma("unroll") for (int k4 = 0; k4 < 4; ++k4) \
    gl16(srcB[k4] + (CHUNK) * 64, &Bb[BUF][(k4 * 256 + wv * 64) * 8]); }

  // ---- one-time: W_out -> LDS (nt==0), z fragments -> registers ----
  if (nt == 0) {
    int r = tid >> 4, s0 = tid & 15;
#pragma unroll
    for (int i = 0; i < 4; ++i) {
      int s = s0 + i * 16;
      unsigned short u[8] = {0, 0, 0, 0, 0, 0, 0, 0};
      if (r < 8) {
        const float* wp = p.wout + (size_t)r * 512 + s * 8;
        float4 f0 = *(const float4*)wp;
        float4 f1 = *(const float4*)(wp + 4);
        u[0] = f2bf(f0.x); u[1] = f2bf(f0.y); u[2] = f2bf(f0.z); u[3] = f2bf(f0.w);
        u[4] = f2bf(f1.x); u[5] = f2bf(f1.y); u[6] = f2bf(f1.z); u[7] = f2bf(f1.w);
      }
      int off = r * 512 + (s >> 3) * 64 + (((s & 7) ^ (r & 7)) * 8);
      *(bf16x8*)&wo[off] = *(bf16x8*)u;
    }
  }
  bf16x8 az[2][2];
#pragma unroll
  for (int m = 0; m < 2; ++m)
#pragma unroll
    for (int ks = 0; ks < 2; ++ks)
      az[m][ks] = *(const bf16x8*)&p.zbf[(size_t)(b0 + mq * 32 + m * 16 + cl) * 64 + ks * 32 + q8 * 8];

  // ---- persistent registers ----
  float bias_r[4];
#pragma unroll
  for (int g = 0; g < 4; ++g) bias_r[g] = p.bias[g * HID + j0 + nh * 16 + cl];
  f32x4 c0 = {0, 0, 0, 0}, c1 = {0, 0, 0, 0};
  f32x4 acc[4][2];
  f32x4 accp0, accp1;
  const float boutv = (cl < 8) ? p.bout[cl] : 0.0f;
  const int arow = tid >> 2, aseg = tid & 3;   // h store mapping

  // A register chunks: ra[buf][m*4 + ks*2 + e]
  u64 ra[2][8];
  const int r0 = b0 + mq * 32 + cl;

  auto loadA = [&](u64 d[8], const unsigned short* hp, int kk) {
    const u64* p0 = (const u64*)(hp + (size_t)r0 * HID) + kk * 16 + q8 * 2;
    const u64* p1 = (const u64*)(hp + (size_t)(r0 + 16) * HID) + kk * 16 + q8 * 2;
#pragma unroll
    for (int ks = 0; ks < 2; ++ks) {
      d[0 + ks * 2 + 0] = ATOMLD(p0 + ks * 8 + 0);
      d[0 + ks * 2 + 1] = ATOMLD(p0 + ks * 8 + 1);
      d[4 + ks * 2 + 0] = ATOMLD(p1 + ks * 8 + 0);
      d[4 + ks * 2 + 1] = ATOMLD(p1 + ks * 8 + 1);
    }
  };

  auto gate_mfma = [&](const u64* ar, bool usez, int kkv) {
    __builtin_amdgcn_s_setprio(1);
#pragma unroll
    for (int ks = 0; ks < 2; ++ks) {
      bf16x8 af0, af1;
      if (usez) { af0 = az[0][ks]; af1 = az[1][ks]; }
      else { af0 = mkfrag(ar[ks * 2], ar[ks * 2 + 1]); af1 = mkfrag(ar[4 + ks * 2], ar[4 + ks * 2 + 1]); }
      const int sx = ((ks * 4 + q8) ^ (cl & 7)) * 8;
      const unsigned short* Bl = Bb[kkv & 1];
#pragma unroll
      for (int g = 0; g < 4; ++g) {
        bf16x8 bf = *(const bf16x8*)&Bl[(g * 32 + nh * 16 + cl) * 64 + sx];
        acc[g][0] = __builtin_amdgcn_mfma_f32_16x16x32_bf16(af0, bf, acc[g][0], 0, 0, 0);
        acc[g][1] = __builtin_amdgcn_mfma_f32_16x16x32_bf16(af1, bf, acc[g][1], 0, 0, 0);
      }
      if (nt == 0 && nh == 0 && kkv < 8) {
        bf16x8 wf = *(const bf16x8*)&wo[cl * 512 + kkv * 64 + sx];
        accp0 = __builtin_amdgcn_mfma_f32_16x16x32_bf16(af0, wf, accp0, 0, 0, 0);
        accp1 = __builtin_amdgcn_mfma_f32_16x16x32_bf16(af1, wf, accp1, 0, 0, 0);
      }
    }
    __builtin_amdgcn_s_setprio(0);
  };

  // cell, h stores, next-step B prefetch, flag
  auto cell_store_flag = [&](unsigned short* hcur, int t) {
#pragma unroll
    for (int fm = 0; fm < 2; ++fm) {
      f32x4 cold = fm ? c1 : c0;
      f32x4 cn;
#pragma unroll
      for (int r = 0; r < 4; ++r) {
        float iv = sigm(acc[0][fm][r]);
        float fv = sigm(acc[1][fm][r]);
        float gv = tanh_f(acc[2][fm][r]);
        float ov = sigm(acc[3][fm][r]);
        float cv = fv * cold[r] + iv * gv;
        cn[r] = cv;
        hO[(mq * 32 + fm * 16 + q8 * 4 + r) * 40 + nh * 16 + cl] = f2bf(ov * tanh_f(cv));
      }
      if (fm) c1 = cn; else c0 = cn;
    }
    asm volatile("" ::: "memory");
    __builtin_amdgcn_s_barrier();               // hO ready (lgkm auto-waited by reads)
    asm volatile("s_waitcnt lgkmcnt(0)" ::: "memory");
    u64 u0 = *(const u64*)&hO[arow * 40 + aseg * 8];
    u64 u1 = *(const u64*)&hO[arow * 40 + aseg * 8 + 4];
    u64* dst = (u64*)(hcur + (size_t)(b0 + arow) * HID + j0 + aseg * 8);
    ATOMST(dst, u0);
    ATOMST(dst + 1, u1);
    STAGEB(0, 0);                               // cross-step prefetch of W chunks 0,1
    STAGEB(1, 1);
    asm volatile("s_waitcnt vmcnt(8)" ::: "memory");  // h stores done; B may fly
    __builtin_amdgcn_s_barrier();
    if (tid == 0)
      __hip_atomic_fetch_add(&p.flags[t * 32 + bt], 1, __ATOMIC_RELAXED,
                             __HIP_MEMORY_SCOPE_AGENT);
  };

#define SPIN(IDX) do { if (tid == 0) { \
      while (__hip_atomic_load(&p.flags[IDX], __ATOMIC_RELAXED, \
                               __HIP_MEMORY_SCOPE_AGENT) < 16) \
        __builtin_amdgcn_s_sleep(1); } __syncthreads(); } while (0)

  // ================= t = 0 : z-chunk only =================
  STAGEB(0, 8);
  asm volatile("s_waitcnt vmcnt(0) lgkmcnt(0)" ::: "memory");
  __builtin_amdgcn_s_barrier();
#pragma unroll
  for (int g = 0; g < 4; ++g) {
    f32x4 v = {bias_r[g], bias_r[g], bias_r[g], bias_r[g]};
    acc[g][0] = v; acc[g][1] = v;
  }
  gate_mfma(nullptr, true, 8);
  asm volatile("" ::: "memory");
  __builtin_amdgcn_s_barrier();                 // Bb[0] reads done before prefetch
  cell_store_flag(p.h0, 0);

  // ================= t = 1 .. 63 =================
  for (int t = 1; t < TSTEP; ++t) {
    const unsigned short* hprev = (t & 1) ? p.h0 : p.h1;
    unsigned short* hcur = (t & 1) ? p.h1 : p.h0;
    SPIN((t - 1) * 32 + bt);

    loadA(ra[0], hprev, 0);
    loadA(ra[1], hprev, 1);
    asm volatile("s_waitcnt vmcnt(20)" ::: "memory");   // B(0) landed
    __builtin_amdgcn_s_barrier();

#pragma unroll
    for (int g = 0; g < 4; ++g) {
      f32x4 v = {bias_r[g], bias_r[g], bias_r[g], bias_r[g]};
      acc[g][0] = v; acc[g][1] = v;
    }
    { f32x4 v = {boutv, boutv, boutv, boutv}; accp0 = v; accp1 = v; }

#pragma unroll
    for (int kk = 0; kk <= 8; ++kk) {
      gate_mfma(ra[kk & 1], kk == 8, kk);
      if (kk == 8) break;
      if (kk <= 5) loadA(ra[kk & 1], hprev, kk + 2);
      asm volatile("" ::: "memory");
      __builtin_amdgcn_s_barrier();             // buf[kk&1] reads done
      if (kk <= 6) STAGEB(kk & 1, kk + 2);
      if (kk <= 5)      asm volatile("s_waitcnt vmcnt(12)" ::: "memory");
      else if (kk == 6) asm volatile("s_waitcnt vmcnt(4)" ::: "memory");
      else              asm volatile("s_waitcnt vmcnt(0)" ::: "memory");
      __builtin_amdgcn_s_barrier();             // next chunk visible
    }
    asm volatile("" ::: "memory");
    __builtin_amdgcn_s_barrier();               // Bb[0] reads (kk=8) done

    if (nt == 0 && nh == 0 && cl < 8) {
      const int tt = t - 1;
#pragma unroll
      for (int r = 0; r < 4; ++r) {
        int b = b0 + mq * 32 + q8 * 4 + r;
        p.out[((size_t)b * 64 + tt) * 8 + cl] = accp0[r];
        p.out[((size_t)(b + 16) * 64 + tt) * 8 + cl] = accp1[r];
      }
    }
    cell_store_flag(hcur, t);
  }

  // ================= epilogue: projection of h(63), nt==0 WGs =================
  if (nt == 0) {
    SPIN(63 * 32 + bt);
    const unsigned short* h63 = p.h1;           // t=63 wrote h1
    u64 rr[2][8];
    loadA(rr[0], h63, 0);
    f32x4 ap0 = {boutv, boutv, boutv, boutv};
    f32x4 ap1 = ap0;
#pragma unroll
    for (int kk = 0; kk < 8; ++kk) {
      if (kk < 7) loadA(rr[(kk + 1) & 1], h63, kk + 1);
      if (nh == 0) {
#pragma unroll
        for (int ks = 0; ks < 2; ++ks) {
          bf16x8 af0 = mkfrag(rr[kk & 1][ks * 2], rr[kk & 1][ks * 2 + 1]);
          bf16x8 af1 = mkfrag(rr[kk & 1][4 + ks * 2], rr[kk & 1][4 + ks * 2 + 1]);
          const int sx = ((ks * 4 + q8) ^ (cl & 7)) * 8;
          bf16x8 wf = *(const bf16x8*)&wo[cl * 512 + kk * 64 + sx];
          ap0 = __builtin_amdgcn_mfma_f32_16x16x32_bf16(af0, wf, ap0, 0, 0, 0);
          ap1 = __builtin_amdgcn_mfma_f32_16x16x32_bf16(af1, wf, ap1, 0, 0, 0);
        }
      }
    }
    if (nh == 0 && cl < 8) {
#pragma unroll
      for (int r = 0; r < 4; ++r) {
        int b = b0 + mq * 32 + q8 * 4 + r;
        p.out[((size_t)b * 64 + 63) * 8 + cl] = ap0[r];
        p.out[((size_t)(b + 16) * 64 + 63) * 8 + cl] = ap1[r];
      }
    }
  }
#undef STAGEB
#undef SPIN
}

// ================= fallback: round-9 multi-launch (passed @926us) =================
__device__ inline void gl16f(const unsigned short* g, unsigned short* l) { gl16(g, l); }

template <int GATES, int PROJ>
__global__ __launch_bounds__(256, 2) void k_stepF(
    const unsigned short* __restrict__ hprev, unsigned short* __restrict__ hnext,
    const unsigned short* __restrict__ wcat, const unsigned short* __restrict__ zbf,
    const float* __restrict__ wout, const float* __restrict__ bias,
    const float* __restrict__ bout, float* __restrict__ cst,
    float* __restrict__ out, int t) {
  __shared__ unsigned short Ab[2][64 * 64];
  __shared__ unsigned short Bb[2][128 * 64];
  __shared__ unsigned short wo_lds[16 * 512];
  __shared__ unsigned short hO[64 * 40];

  const int bid = blockIdx.x;
  const int nt = GATES ? (((bid & 7) << 1) | ((bid >> 8) & 1)) : 0;
  const int bt = GATES ? ((bid >> 3) & 31) : bid;
  const int tid = threadIdx.x;
  const int lane = tid & 63;
  const int wv = tid >> 6;
  const int mq = wv >> 1, nh = wv & 1;
  const int cl = lane & 15, q8 = lane >> 4;
  const int b0 = bt * 64, j0 = nt * 32;

  const int rA = tid >> 3;
  const int xA = ((tid & 7) ^ (rA & 7)) * 8;
  const unsigned short* srcA0 = hprev + (size_t)(b0 + rA) * HID + xA;
  const unsigned short* srcA1 = hprev + (size_t)(b0 + 32 + rA) * HID + xA;
  const unsigned short* srcZ0 = zbf + (size_t)(b0 + rA) * 64 + xA;
  const unsigned short* srcZ1 = zbf + (size_t)(b0 + 32 + rA) * 64 + xA;
  const unsigned short* srcB[4];
#pragma unroll
  for (int k = 0; k < 4; ++k) {
    int rB = k * 32 + rA;
    int n = (rB >> 5) * HID + j0 + (rB & 31);
    srcB[k] = wcat + (size_t)n * KCAT + xA;
  }

  auto do_stage = [&](int buf, int kkv) {
    if (GATES) {
      if (kkv == 8) {
        gl16f(srcZ0, &Ab[buf][(wv * 64) * 8]);
        gl16f(srcZ1, &Ab[buf][(256 + wv * 64) * 8]);
      } else {
        gl16f(srcA0 + kkv * 64, &Ab[buf][(wv * 64) * 8]);
        gl16f(srcA1 + kkv * 64, &Ab[buf][(256 + wv * 64) * 8]);
      }
#pragma unroll
      for (int k = 0; k < 4; ++k)
        gl16f(srcB[k] + kkv * 64, &Bb[buf][(k * 256 + wv * 64) * 8]);
    } else {
      gl16f(srcA0 + kkv * 64, &Ab[buf][(wv * 64) * 8]);
      gl16f(srcA1 + kkv * 64, &Ab[buf][(256 + wv * 64) * 8]);
    }
  };

  if (PROJ) {
    int r = tid >> 4, s0 = tid & 15;
#pragma unroll
    for (int i = 0; i < 4; ++i) {
      int s = s0 + i * 16;
      unsigned short u[8] = {0, 0, 0, 0, 0, 0, 0, 0};
      if (r < 8) {
        const float* wp = wout + (size_t)r * 512 + s * 8;
        float4 f0 = *(const float4*)wp;
        float4 f1 = *(const float4*)(wp + 4);
        u[0] = f2bf(f0.x); u[1] = f2bf(f0.y); u[2] = f2bf(f0.z); u[3] = f2bf(f0.w);
        u[4] = f2bf(f1.x); u[5] = f2bf(f1.y); u[6] = f2bf(f1.z); u[7] = f2bf(f1.w);
      }
      int off = r * 512 + (s >> 3) * 64 + (((s & 7) ^ (r & 7)) * 8);
      *(bf16x8*)&wo_lds[off] = *(bf16x8*)u;
    }
  }

  f32x4 acc[4][2];
  if (GATES) {
#pragma unroll
    for (int g = 0; g < 4; ++g) {
      float bv = bias[g * HID + j0 + nh * 16 + cl];
      f32x4 v = {bv, bv, bv, bv};
      acc[g][0] = v; acc[g][1] = v;
    }
  }
  f32x4 accp0 = {0, 0, 0, 0}, accp1 = {0, 0, 0, 0};
  if (PROJ) {
    float bo = (cl < 8) ? bout[cl] : 0.0f;
    f32x4 v = {bo, bo, bo, bo};
    accp0 = v; accp1 = v;
  }

  const size_t cbase = ((size_t)bid * 256 + tid) * 8;
  f32x4 c0 = {0, 0, 0, 0}, c1 = {0, 0, 0, 0};
  if (GATES && t > 0) { c0 = *(const f32x4*)&cst[cbase]; c1 = *(const f32x4*)&cst[cbase + 4]; }

  auto mfma_block = [&](int bu, int kkv) {
    const unsigned short* Al = Ab[bu];
    const unsigned short* Bl = Bb[bu];
#pragma unroll
    for (int ks = 0; ks < 2; ++ks) {
      const int sx = ((ks * 4 + q8) ^ (cl & 7)) * 8;
      bf16x8 af0 = *(const bf16x8*)&Al[(mq * 32 + cl) * 64 + sx];
      bf16x8 af1 = *(const bf16x8*)&Al[(mq * 32 + 16 + cl) * 64 + sx];
      if (GATES) {
#pragma unroll
        for (int g = 0; g < 4; ++g) {
          bf16x8 bf = *(const bf16x8*)&Bl[(g * 32 + nh * 16 + cl) * 64 + sx];
          acc[g][0] = __builtin_amdgcn_mfma_f32_16x16x32_bf16(af0, bf, acc[g][0], 0, 0, 0);
          acc[g][1] = __builtin_amdgcn_mfma_f32_16x16x32_bf16(af1, bf, acc[g][1], 0, 0, 0);
        }
      }
      if (PROJ && nh == 0 && kkv < 8) {
        bf16x8 wf = *(const bf16x8*)&wo_lds[cl * 512 + kkv * 64 + sx];
        accp0 = __builtin_amdgcn_mfma_f32_16x16x32_bf16(af0, wf, accp0, 0, 0, 0);
        accp1 = __builtin_amdgcn_mfma_f32_16x16x32_bf16(af1, wf, accp1, 0, 0, 0);
      }
    }
  };

  if (GATES && t == 0) {
    do_stage(0, 8);
    asm volatile("s_waitcnt vmcnt(0) lgkmcnt(0)" ::: "memory");
    __builtin_amdgcn_s_barrier();
    mfma_block(0, 8);
  } else {
    do_stage(0, 0);
    do_stage(1, 1);
    if (GATES) asm volatile("s_waitcnt vmcnt(6) lgkmcnt(0)" ::: "memory");
    else       asm volatile("s_waitcnt vmcnt(2) lgkmcnt(0)" ::: "memory");
    __builtin_amdgcn_s_barrier();
    const int kkEnd = GATES ? 8 : 7;
    for (int kk = 0;; ++kk) {
      mfma_block(kk & 1, kk);
      if (kk == kkEnd) break;
      asm volatile("" ::: "memory");
      __builtin_amdgcn_s_barrier();
      if (kk + 2 <= kkEnd) {
        do_stage(kk & 1, kk + 2);
        if (GATES) asm volatile("s_waitcnt vmcnt(6)" ::: "memory");
        else       asm volatile("s_waitcnt vmcnt(2)" ::: "memory");
      } else {
        asm volatile("s_waitcnt vmcnt(0)" ::: "memory");
      }
      asm volatile("" ::: "memory");
      __builtin_amdgcn_s_barrier();
    }
  }

  if (PROJ && nh == 0 && cl < 8) {
    const int tt = t - 1;
#pragma unroll
    for (int r = 0; r < 4; ++r) {
      int b = b0 + mq * 32 + q8 * 4 + r;
      out[((size_t)b * 64 + tt) * 8 + cl] = accp0[r];
      out[((size_t)(b + 16) * 64 + tt) * 8 + cl] = accp1[r];
    }
  }

  if (GATES) {
#pragma unroll
    for (int fm = 0; fm < 2; ++fm) {
      f32x4 cold = fm ? c1 : c0;
      f32x4 cn;
#pragma unroll
      for (int r = 0; r < 4; ++r) {
        float iv = sigm(acc[0][fm][r]);
        float fv = sigm(acc[1][fm][r]);
        float gv = tanh_f(acc[2][fm][r]);
        float ov = sigm(acc[3][fm][r]);
        float cv = fv * cold[r] + iv * gv;
        cn[r] = cv;
        hO[(mq * 32 + fm * 16 + q8 * 4 + r) * 40 + nh * 16 + cl] = f2bf(ov * tanh_f(cv));
      }
      if (fm) c1 = cn; else c0 = cn;
    }
    *(f32x4*)&cst[cbase] = c0;
    *(f32x4*)&cst[cbase + 4] = c1;
    __syncthreads();
    int row = tid >> 2, sg4 = tid & 3;
    unsigned short tmp[8];
#pragma unroll
    for (int e = 0; e < 8; ++e) tmp[e] = hO[row * 40 + sg4 * 8 + e];
    *(int4*)&hnext[(size_t)(b0 + row) * HID + j0 + sg4 * 8] = *(int4*)tmp;
  }
}

extern "C" void kernel_launch(void* const* d_in, const int* in_sizes, int n_in,
                              void* d_out, int out_size, void* d_ws, size_t ws_size,
                              hipStream_t stream) {
  const float* z    = (const float*)d_in[0];
  const float* wih  = (const float*)d_in[1];
  const float* whh  = (const float*)d_in[2];
  const float* bih  = (const float*)d_in[3];
  const float* bhh  = (const float*)d_in[4];
  const float* wout = (const float*)d_in[5];
  const float* bout = (const float*)d_in[6];
  float* out = (float*)d_out;

  char* ws = (char*)d_ws;
  unsigned short* wcat = (unsigned short*)(ws);              // 2,359,296
  unsigned short* zbf  = (unsigned short*)(ws + 2359296);    //   262,144
  float* bias          = (float*)(ws + 2621440);             //     8,192
  unsigned short* h0   = (unsigned short*)(ws + 2629632);    // 2,097,152
  unsigned short* h1   = (unsigned short*)(ws + 4726784);    // 2,097,152
  int* flags           = (int*)(ws + 6823936);               //     8,192
  float* cst           = (float*)(ws + 6832128);             // 4,194,304 (fallback)

  k_prep<<<dim3(648), dim3(256), 0, stream>>>(z, wih, whh, bih, bhh, wcat, zbf, bias);
  k_zero<<<dim3(8), dim3(256), 0, stream>>>(flags);

  P pp;
  pp.wcat = wcat; pp.zbf = zbf; pp.bias = bias; pp.wout = wout; pp.bout = bout;
  pp.h0 = h0; pp.h1 = h1; pp.out = out; pp.flags = flags;

  void* args[] = {&pp};
  hipError_t e = hipLaunchCooperativeKernel((const void*)k_persist, dim3(512), dim3(256),
                                            args, 0, stream);
  if (e == hipSuccess) return;

  for (int t = 0; t < TSTEP; ++t) {
    const unsigned short* hp = (t & 1) ? h0 : h1;
    unsigned short* hn = (t & 1) ? h1 : h0;
    if (t == 0)
      k_stepF<1, 0><<<dim3(512), dim3(256), 0, stream>>>(hp, hn, wcat, zbf, wout, bias,
                                                         bout, cst, out, t);
    else
      k_stepF<1, 1><<<dim3(512), dim3(256), 0, stream>>>(hp, hn, wcat, zbf, wout, bias,
                                                         bout, cst, out, t);
  }
  k_stepF<0, 1><<<dim3(32), dim3(256), 0, stream>>>(h1, h0, wcat, zbf, wout, bias,
                                                    bout, cst, out, TSTEP);
}

// Round 13
// 911.657 us; speedup vs baseline: 1.9445x; 1.9445x over previous
//
#include <hip/hip_runtime.h>

// LSTM decoder B=2048, Z=64, A=8, H=512, T=64.
// Round 13: r12 persistent kernel with CORRECTED vmcnt budgets (r12 raced:
// WAITV(12) in steady state did not guarantee B(kk+1)'s LDS landing before
// its ds_read -> stale LDS on replay). Derived budgets:
//   prologue WAITV(8) ; kk=0: 12 ; kk=1..4: 8 ; kk=5,6: 4 ; kk=7: 0.
// Everything else identical to r12. Fallback: r9 multi-launch (926 us).

#define HID   512
#define TSTEP 64
#define KCAT  576

typedef unsigned long long u64;
typedef __attribute__((ext_vector_type(8))) short bf16x8;
typedef __attribute__((ext_vector_type(4))) float f32x4;

__device__ inline unsigned short f2bf(float f) {
  unsigned int u = __builtin_bit_cast(unsigned int, f);
  unsigned int r = (u + 0x7fffu + ((u >> 16) & 1u)) >> 16;
  return (unsigned short)r;
}
__device__ inline float sigm(float x) { return 1.0f / (1.0f + __expf(-x)); }
__device__ inline float tanh_f(float x) { return 1.0f - 2.0f / (__expf(2.0f * x) + 1.0f); }

__device__ inline void gl16(const unsigned short* g, unsigned short* l) {
  __builtin_amdgcn_global_load_lds(
      (const __attribute__((address_space(1))) unsigned int*)g,
      (__attribute__((address_space(3))) unsigned int*)l, 16, 0, 0);
}
// coherent 16B load (agent scope: bypasses L1 + non-coherent L2)
__device__ inline void ldc16(bf16x8& d, const unsigned short* p) {
  asm volatile("global_load_dwordx4 %0, %1, off sc0 sc1"
               : "=v"(d) : "v"(p) : "memory");
}

#define ATOMLD(PTR) __hip_atomic_load((PTR), __ATOMIC_RELAXED, __HIP_MEMORY_SCOPE_AGENT)
#define ATOMST(PTR, V) __hip_atomic_store((PTR), (V), __ATOMIC_RELAXED, __HIP_MEMORY_SCOPE_AGENT)
#define WAITV(N) do { asm volatile("s_waitcnt vmcnt(" #N ")" ::: "memory"); \
                      __builtin_amdgcn_sched_barrier(0); } while (0)

// ---- merged prep ----
__global__ void k_prep(const float* __restrict__ z, const float* __restrict__ wih,
                       const float* __restrict__ whh, const float* __restrict__ bih,
                       const float* __restrict__ bhh,
                       unsigned short* __restrict__ wcat, unsigned short* __restrict__ zbf,
                       float* __restrict__ bias) {
  int c = blockIdx.x * 256 + threadIdx.x;
  if (c < 147456) {
    int n = c / 72, kc = (c % 72) * 8;
    unsigned short u[8];
#pragma unroll
    for (int e = 0; e < 8; ++e) {
      int k = kc + e;
      float v = (k < 512) ? whh[(size_t)n * 512 + k] : wih[(size_t)n * 72 + 8 + (k - 512)];
      u[e] = f2bf(v);
    }
    *(bf16x8*)&wcat[(size_t)n * KCAT + kc] = *(bf16x8*)u;
  } else if (c < 163840) {
    int i = c - 147456;
    int row = i >> 3, kc = (i & 7) * 8;
    unsigned short u[8];
#pragma unroll
    for (int e = 0; e < 8; ++e) u[e] = f2bf(z[(size_t)row * 64 + kc + e]);
    *(bf16x8*)&zbf[(size_t)row * 64 + kc] = *(bf16x8*)u;
  } else if (c < 165888) {
    int n = c - 163840;
    bias[n] = bih[n] + bhh[n];
  }
}

__global__ void k_zero(int* __restrict__ flags) {
  int g = blockIdx.x * 256 + threadIdx.x;
  if (g < TSTEP * 512) flags[g] = 0;
}

struct P {
  const unsigned short *wcat, *zbf;
  const float *bias, *wout, *bout;
  unsigned short *h0, *h1;
  float* out;
  int* flags;
};

// LDS: Bb0 0 | Bb1 16384 | Bb2 32768 | wo 49152 | hO 65536 ; total 70656
#define SMEM_SZ 70656

__global__ __launch_bounds__(256, 2) void k_persist(P p) {
  extern __shared__ char smem[];
  unsigned short* Bb[3] = {(unsigned short*)smem, (unsigned short*)(smem + 16384),
                           (unsigned short*)(smem + 32768)};
  unsigned short* wo = (unsigned short*)(smem + 49152);
  unsigned short* hO = (unsigned short*)(smem + 65536);

  const int bid = blockIdx.x;
  const int nt = bid >> 5, bt = bid & 31;
  const int tid = threadIdx.x;
  const int lane = tid & 63;
  const int wv = tid >> 6;
  const int mq = wv >> 1, nh = wv & 1;
  const int cl = lane & 15, q8 = lane >> 4;
  const int b0 = bt * 64, j0 = nt * 32;

  // ---- B staging (verified pattern) ----
  const int rS = tid >> 3;
  const int xS = ((tid & 7) ^ (rS & 7)) * 8;
  const unsigned short* srcB[4];
#pragma unroll
  for (int k = 0; k < 4; ++k) {
    int rB = k * 32 + rS;
    int n = (rB >> 5) * HID + j0 + (rB & 31);
    srcB[k] = p.wcat + (size_t)n * KCAT + xS;
  }
#define STAGEB(BUF, CHUNK) { _Pragma("unroll") for (int k4 = 0; k4 < 4; ++k4) \
    gl16(srcB[k4] + (CHUNK) * 64, &Bb[BUF][(k4 * 256 + wv * 64) * 8]); }

  // ---- one-time: W_out -> LDS (nt==0), z frags -> regs ----
  if (nt == 0) {
    int r = tid >> 4, s0 = tid & 15;
#pragma unroll
    for (int i = 0; i < 4; ++i) {
      int s = s0 + i * 16;
      unsigned short u[8] = {0, 0, 0, 0, 0, 0, 0, 0};
      if (r < 8) {
        const float* wp = p.wout + (size_t)r * 512 + s * 8;
        float4 f0 = *(const float4*)wp;
        float4 f1 = *(const float4*)(wp + 4);
        u[0] = f2bf(f0.x); u[1] = f2bf(f0.y); u[2] = f2bf(f0.z); u[3] = f2bf(f0.w);
        u[4] = f2bf(f1.x); u[5] = f2bf(f1.y); u[6] = f2bf(f1.z); u[7] = f2bf(f1.w);
      }
      int off = r * 512 + (s >> 3) * 64 + (((s & 7) ^ (r & 7)) * 8);
      *(bf16x8*)&wo[off] = *(bf16x8*)u;
    }
  }
  bf16x8 azr[4];
#pragma unroll
  for (int m = 0; m < 2; ++m)
#pragma unroll
    for (int ks = 0; ks < 2; ++ks)
      azr[m * 2 + ks] = *(const bf16x8*)&p.zbf[(size_t)(b0 + mq * 32 + m * 16 + cl) * 64 + ks * 32 + q8 * 8];

  // ---- persistent registers ----
  float bias_r[4];
#pragma unroll
  for (int g = 0; g < 4; ++g) bias_r[g] = p.bias[g * HID + j0 + nh * 16 + cl];
  f32x4 c0 = {0, 0, 0, 0}, c1 = {0, 0, 0, 0};
  f32x4 acc[4][2];
  f32x4 accp0, accp1;
  const float boutv = (cl < 8) ? p.bout[cl] : 0.0f;
  const int arow = tid >> 2, aseg = tid & 3;   // h store mapping
  const int r0 = b0 + mq * 32 + cl;

  bf16x8 ra[3][4];
  auto issueA = [&](bf16x8 d[4], const unsigned short* hp, int kk) {
    const unsigned short* base0 = hp + (size_t)r0 * HID + kk * 64 + q8 * 8;
    const unsigned short* base1 = base0 + 16 * HID;
    ldc16(d[0], base0);
    ldc16(d[1], base0 + 32);
    ldc16(d[2], base1);
    ldc16(d[3], base1 + 32);
  };

  auto gate_mfma = [&](const bf16x8 a4[4], const unsigned short* Bl, int kkv) {
    __builtin_amdgcn_s_setprio(1);
#pragma unroll
    for (int ks = 0; ks < 2; ++ks) {
      const int sx = ((ks * 4 + q8) ^ (cl & 7)) * 8;
      bf16x8 af0 = a4[ks], af1 = a4[2 + ks];
#pragma unroll
      for (int g = 0; g < 4; ++g) {
        bf16x8 bf = *(const bf16x8*)&Bl[(g * 32 + nh * 16 + cl) * 64 + sx];
        acc[g][0] = __builtin_amdgcn_mfma_f32_16x16x32_bf16(af0, bf, acc[g][0], 0, 0, 0);
        acc[g][1] = __builtin_amdgcn_mfma_f32_16x16x32_bf16(af1, bf, acc[g][1], 0, 0, 0);
      }
      if (nt == 0 && nh == 0 && kkv < 8) {
        bf16x8 wf = *(const bf16x8*)&wo[cl * 512 + kkv * 64 + sx];
        accp0 = __builtin_amdgcn_mfma_f32_16x16x32_bf16(af0, wf, accp0, 0, 0, 0);
        accp1 = __builtin_amdgcn_mfma_f32_16x16x32_bf16(af1, wf, accp1, 0, 0, 0);
      }
    }
    __builtin_amdgcn_s_setprio(0);
  };

  // cell + h store + cross-step B prefetch + flag
  auto cell_store_flag = [&](unsigned short* hcur, int t) {
#pragma unroll
    for (int fm = 0; fm < 2; ++fm) {
      f32x4 cold = fm ? c1 : c0;
      f32x4 cn;
#pragma unroll
      for (int r = 0; r < 4; ++r) {
        float iv = sigm(acc[0][fm][r]);
        float fv = sigm(acc[1][fm][r]);
        float gv = tanh_f(acc[2][fm][r]);
        float ov = sigm(acc[3][fm][r]);
        float cv = fv * cold[r] + iv * gv;
        cn[r] = cv;
        hO[(mq * 32 + fm * 16 + q8 * 4 + r) * 40 + nh * 16 + cl] = f2bf(ov * tanh_f(cv));
      }
      if (fm) c1 = cn; else c0 = cn;
    }
    __syncthreads();                            // hO ready; all waves past MFMA(8)
    u64 u0 = *(const u64*)&hO[arow * 40 + aseg * 8];
    u64 u1 = *(const u64*)&hO[arow * 40 + aseg * 8 + 4];
    u64* dst = (u64*)(hcur + (size_t)(b0 + arow) * HID + j0 + aseg * 8);
    ATOMST(dst, u0);
    ATOMST(dst + 1, u1);
    STAGEB(0, 0);                               // next-step W prefetch (h-independent)
    STAGEB(1, 1);
    WAITV(8);                                   // own h stores complete; B0,B1 may fly
    __builtin_amdgcn_s_barrier();               // everyone's h stores complete
    if (tid == 0)
      ATOMST(&p.flags[t * 512 + bt * 16 + nt], 1);
  };

#define SPIN(T) do { \
    if (tid < 16) { \
      const int* fp = &p.flags[(T) * 512 + bt * 16 + tid]; \
      while (ATOMLD(fp) == 0) __builtin_amdgcn_s_sleep(1); \
    } \
    __syncthreads(); } while (0)

  // ================= t = 0 : z-chunk only =================
  STAGEB(2, 8);
  asm volatile("s_waitcnt vmcnt(0) lgkmcnt(0)" ::: "memory");
  __builtin_amdgcn_sched_barrier(0);
  __builtin_amdgcn_s_barrier();
#pragma unroll
  for (int g = 0; g < 4; ++g) {
    f32x4 v = {bias_r[g], bias_r[g], bias_r[g], bias_r[g]};
    acc[g][0] = v; acc[g][1] = v;
  }
  gate_mfma(azr, Bb[2], 8);
  cell_store_flag(p.h0, 0);

  // ================= t = 1 .. 63 =================
  for (int t = 1; t < TSTEP; ++t) {
    const unsigned short* hprev = (t & 1) ? p.h0 : p.h1;
    unsigned short* hcur = (t & 1) ? p.h1 : p.h0;
    SPIN(t - 1);

    issueA(ra[0], hprev, 0);
    issueA(ra[1], hprev, 1);
    issueA(ra[2], hprev, 2);
    WAITV(8);                                   // retires B0,B1,A0
    __builtin_amdgcn_s_barrier();

#pragma unroll
    for (int g = 0; g < 4; ++g) {
      f32x4 v = {bias_r[g], bias_r[g], bias_r[g], bias_r[g]};
      acc[g][0] = v; acc[g][1] = v;
    }
    { f32x4 v = {boutv, boutv, boutv, boutv}; accp0 = v; accp1 = v; }

#pragma unroll
    for (int kk = 0; kk <= 8; ++kk) {
      gate_mfma(kk < 8 ? ra[kk % 3] : azr, Bb[kk % 3], kk);
      if (kk == 8) break;
      if (kk <= 4) issueA(ra[kk % 3], hprev, kk + 3);
      if (kk <= 6) STAGEB((kk + 2) % 3, kk + 2);
      // Corrected budgets (r12 bug): guarantee A(kk+1) AND B(kk+1) landed.
      if (kk == 0)      WAITV(12);   // retires A1          (B1 landed in prologue)
      else if (kk <= 4) WAITV(8);    // retires A(kk+1),A(kk+2),B(kk+1)
      else if (kk <= 6) WAITV(4);    // kk=5: A7,B6 ; kk=6: B7
      else              WAITV(0);    // kk=7: B8
      __builtin_amdgcn_s_barrier();
    }

    if (nt == 0 && nh == 0 && cl < 8) {
      const int tt = t - 1;
#pragma unroll
      for (int r = 0; r < 4; ++r) {
        int b = b0 + mq * 32 + q8 * 4 + r;
        p.out[((size_t)b * 64 + tt) * 8 + cl] = accp0[r];
        p.out[((size_t)(b + 16) * 64 + tt) * 8 + cl] = accp1[r];
      }
    }
    cell_store_flag(hcur, t);
  }

  // ================= epilogue: projection of h(63), nt==0 WGs =================
  if (nt == 0) {
    SPIN(63);
    const unsigned short* h63 = p.h1;           // t=63 wrote h1
    issueA(ra[0], h63, 0);
    issueA(ra[1], h63, 1);
    issueA(ra[2], h63, 2);
    f32x4 ap0 = {boutv, boutv, boutv, boutv};
    f32x4 ap1 = ap0;
#pragma unroll
    for (int kk = 0; kk < 8; ++kk) {
      if (kk <= 5)      WAITV(8);
      else if (kk == 6) WAITV(4);
      else              WAITV(0);
      if (nh == 0) {
#pragma unroll
        for (int ks = 0; ks < 2; ++ks) {
          const int sx = ((ks * 4 + q8) ^ (cl & 7)) * 8;
          bf16x8 wf = *(const bf16x8*)&wo[cl * 512 + kk * 64 + sx];
          ap0 = __builtin_amdgcn_mfma_f32_16x16x32_bf16(ra[kk % 3][ks], wf, ap0, 0, 0, 0);
          ap1 = __builtin_amdgcn_mfma_f32_16x16x32_bf16(ra[kk % 3][2 + ks], wf, ap1, 0, 0, 0);
        }
      }
      if (kk <= 4) issueA(ra[kk % 3], h63, kk + 3);
    }
    if (nh == 0 && cl < 8) {
#pragma unroll
      for (int r = 0; r < 4; ++r) {
        int b = b0 + mq * 32 + q8 * 4 + r;
        p.out[((size_t)b * 64 + 63) * 8 + cl] = ap0[r];
        p.out[((size_t)(b + 16) * 64 + 63) * 8 + cl] = ap1[r];
      }
    }
  }
#undef STAGEB
#undef SPIN
}

// ================= fallback: round-9 multi-launch (passed @926us) =================
template <int GATES, int PROJ>
__global__ __launch_bounds__(256, 2) void k_stepF(
    const unsigned short* __restrict__ hprev, unsigned short* __restrict__ hnext,
    const unsigned short* __restrict__ wcat, const unsigned short* __restrict__ zbf,
    const float* __restrict__ wout, const float* __restrict__ bias,
    const float* __restrict__ bout, float* __restrict__ cst,
    float* __restrict__ out, int t) {
  __shared__ unsigned short Ab[2][64 * 64];
  __shared__ unsigned short Bb[2][128 * 64];
  __shared__ unsigned short wo_lds[16 * 512];
  __shared__ unsigned short hO[64 * 40];

  const int bid = blockIdx.x;
  const int nt = GATES ? (((bid & 7) << 1) | ((bid >> 8) & 1)) : 0;
  const int bt = GATES ? ((bid >> 3) & 31) : bid;
  const int tid = threadIdx.x;
  const int lane = tid & 63;
  const int wv = tid >> 6;
  const int mq = wv >> 1, nh = wv & 1;
  const int cl = lane & 15, q8 = lane >> 4;
  const int b0 = bt * 64, j0 = nt * 32;

  const int rA = tid >> 3;
  const int xA = ((tid & 7) ^ (rA & 7)) * 8;
  const unsigned short* srcA0 = hprev + (size_t)(b0 + rA) * HID + xA;
  const unsigned short* srcA1 = hprev + (size_t)(b0 + 32 + rA) * HID + xA;
  const unsigned short* srcZ0 = zbf + (size_t)(b0 + rA) * 64 + xA;
  const unsigned short* srcZ1 = zbf + (size_t)(b0 + 32 + rA) * 64 + xA;
  const unsigned short* srcB[4];
#pragma unroll
  for (int k = 0; k < 4; ++k) {
    int rB = k * 32 + rA;
    int n = (rB >> 5) * HID + j0 + (rB & 31);
    srcB[k] = wcat + (size_t)n * KCAT + xA;
  }

  auto do_stage = [&](int buf, int kkv) {
    if (GATES) {
      if (kkv == 8) {
        gl16(srcZ0, &Ab[buf][(wv * 64) * 8]);
        gl16(srcZ1, &Ab[buf][(256 + wv * 64) * 8]);
      } else {
        gl16(srcA0 + kkv * 64, &Ab[buf][(wv * 64) * 8]);
        gl16(srcA1 + kkv * 64, &Ab[buf][(256 + wv * 64) * 8]);
      }
#pragma unroll
      for (int k = 0; k < 4; ++k)
        gl16(srcB[k] + kkv * 64, &Bb[buf][(k * 256 + wv * 64) * 8]);
    } else {
      gl16(srcA0 + kkv * 64, &Ab[buf][(wv * 64) * 8]);
      gl16(srcA1 + kkv * 64, &Ab[buf][(256 + wv * 64) * 8]);
    }
  };

  if (PROJ) {
    int r = tid >> 4, s0 = tid & 15;
#pragma unroll
    for (int i = 0; i < 4; ++i) {
      int s = s0 + i * 16;
      unsigned short u[8] = {0, 0, 0, 0, 0, 0, 0, 0};
      if (r < 8) {
        const float* wp = wout + (size_t)r * 512 + s * 8;
        float4 f0 = *(const float4*)wp;
        float4 f1 = *(const float4*)(wp + 4);
        u[0] = f2bf(f0.x); u[1] = f2bf(f0.y); u[2] = f2bf(f0.z); u[3] = f2bf(f0.w);
        u[4] = f2bf(f1.x); u[5] = f2bf(f1.y); u[6] = f2bf(f1.z); u[7] = f2bf(f1.w);
      }
      int off = r * 512 + (s >> 3) * 64 + (((s & 7) ^ (r & 7)) * 8);
      *(bf16x8*)&wo_lds[off] = *(bf16x8*)u;
    }
  }

  f32x4 acc[4][2];
  if (GATES) {
#pragma unroll
    for (int g = 0; g < 4; ++g) {
      float bv = bias[g * HID + j0 + nh * 16 + cl];
      f32x4 v = {bv, bv, bv, bv};
      acc[g][0] = v; acc[g][1] = v;
    }
  }
  f32x4 accp0 = {0, 0, 0, 0}, accp1 = {0, 0, 0, 0};
  if (PROJ) {
    float bo = (cl < 8) ? bout[cl] : 0.0f;
    f32x4 v = {bo, bo, bo, bo};
    accp0 = v; accp1 = v;
  }

  const size_t cbase = ((size_t)bid * 256 + tid) * 8;
  f32x4 c0 = {0, 0, 0, 0}, c1 = {0, 0, 0, 0};
  if (GATES && t > 0) { c0 = *(const f32x4*)&cst[cbase]; c1 = *(const f32x4*)&cst[cbase + 4]; }

  auto mfma_block = [&](int bu, int kkv) {
    const unsigned short* Al = Ab[bu];
    const unsigned short* Bl = Bb[bu];
#pragma unroll
    for (int ks = 0; ks < 2; ++ks) {
      const int sx = ((ks * 4 + q8) ^ (cl & 7)) * 8;
      bf16x8 af0 = *(const bf16x8*)&Al[(mq * 32 + cl) * 64 + sx];
      bf16x8 af1 = *(const bf16x8*)&Al[(mq * 32 + 16 + cl) * 64 + sx];
      if (GATES) {
#pragma unroll
        for (int g = 0; g < 4; ++g) {
          bf16x8 bf = *(const bf16x8*)&Bl[(g * 32 + nh * 16 + cl) * 64 + sx];
          acc[g][0] = __builtin_amdgcn_mfma_f32_16x16x32_bf16(af0, bf, acc[g][0], 0, 0, 0);
          acc[g][1] = __builtin_amdgcn_mfma_f32_16x16x32_bf16(af1, bf, acc[g][1], 0, 0, 0);
        }
      }
      if (PROJ && nh == 0 && kkv < 8) {
        bf16x8 wf = *(const bf16x8*)&wo_lds[cl * 512 + kkv * 64 + sx];
        accp0 = __builtin_amdgcn_mfma_f32_16x16x32_bf16(af0, wf, accp0, 0, 0, 0);
        accp1 = __builtin_amdgcn_mfma_f32_16x16x32_bf16(af1, wf, accp1, 0, 0, 0);
      }
    }
  };

  if (GATES && t == 0) {
    do_stage(0, 8);
    asm volatile("s_waitcnt vmcnt(0) lgkmcnt(0)" ::: "memory");
    __builtin_amdgcn_s_barrier();
    mfma_block(0, 8);
  } else {
    do_stage(0, 0);
    do_stage(1, 1);
    if (GATES) asm volatile("s_waitcnt vmcnt(6) lgkmcnt(0)" ::: "memory");
    else       asm volatile("s_waitcnt vmcnt(2) lgkmcnt(0)" ::: "memory");
    __builtin_amdgcn_s_barrier();
    const int kkEnd = GATES ? 8 : 7;
    for (int kk = 0;; ++kk) {
      mfma_block(kk & 1, kk);
      if (kk == kkEnd) break;
      asm volatile("" ::: "memory");
      __builtin_amdgcn_s_barrier();
      if (kk + 2 <= kkEnd) {
        do_stage(kk & 1, kk + 2);
        if (GATES) asm volatile("s_waitcnt vmcnt(6)" ::: "memory");
        else       asm volatile("s_waitcnt vmcnt(2)" ::: "memory");
      } else {
        asm volatile("s_waitcnt vmcnt(0)" ::: "memory");
      }
      asm volatile("" ::: "memory");
      __builtin_amdgcn_s_barrier();
    }
  }

  if (PROJ && nh == 0 && cl < 8) {
    const int tt = t - 1;
#pragma unroll
    for (int r = 0; r < 4; ++r) {
      int b = b0 + mq * 32 + q8 * 4 + r;
      out[((size_t)b * 64 + tt) * 8 + cl] = accp0[r];
      out[((size_t)(b + 16) * 64 + tt) * 8 + cl] = accp1[r];
    }
  }

  if (GATES) {
#pragma unroll
    for (int fm = 0; fm < 2; ++fm) {
      f32x4 cold = fm ? c1 : c0;
      f32x4 cn;
#pragma unroll
      for (int r = 0; r < 4; ++r) {
        float iv = sigm(acc[0][fm][r]);
        float fv = sigm(acc[1][fm][r]);
        float gv = tanh_f(acc[2][fm][r]);
        float ov = sigm(acc[3][fm][r]);
        float cv = fv * cold[r] + iv * gv;
        cn[r] = cv;
        hO[(mq * 32 + fm * 16 + q8 * 4 + r) * 40 + nh * 16 + cl] = f2bf(ov * tanh_f(cv));
      }
      if (fm) c1 = cn; else c0 = cn;
    }
    *(f32x4*)&cst[cbase] = c0;
    *(f32x4*)&cst[cbase + 4] = c1;
    __syncthreads();
    int row = tid >> 2, sg4 = tid & 3;
    unsigned short tmp[8];
#pragma unroll
    for (int e = 0; e < 8; ++e) tmp[e] = hO[row * 40 + sg4 * 8 + e];
    *(int4*)&hnext[(size_t)(b0 + row) * HID + j0 + sg4 * 8] = *(int4*)tmp;
  }
}

extern "C" void kernel_launch(void* const* d_in, const int* in_sizes, int n_in,
                              void* d_out, int out_size, void* d_ws, size_t ws_size,
                              hipStream_t stream) {
  const float* z    = (const float*)d_in[0];
  const float* wih  = (const float*)d_in[1];
  const float* whh  = (const float*)d_in[2];
  const float* bih  = (const float*)d_in[3];
  const float* bhh  = (const float*)d_in[4];
  const float* wout = (const float*)d_in[5];
  const float* bout = (const float*)d_in[6];
  float* out = (float*)d_out;

  char* ws = (char*)d_ws;
  unsigned short* wcat = (unsigned short*)(ws);              // 2,359,296
  unsigned short* zbf  = (unsigned short*)(ws + 2359296);    //   262,144
  float* bias          = (float*)(ws + 2621440);             //     8,192
  unsigned short* h0   = (unsigned short*)(ws + 2629632);    // 2,097,152
  unsigned short* h1   = (unsigned short*)(ws + 4726784);    // 2,097,152
  int* flags           = (int*)(ws + 6823936);               //   131,072
  float* cst           = (float*)(ws + 6955008);             // 4,194,304 (fallback)

  k_prep<<<dim3(648), dim3(256), 0, stream>>>(z, wih, whh, bih, bhh, wcat, zbf, bias);
  k_zero<<<dim3(128), dim3(256), 0, stream>>>(flags);

  P pp;
  pp.wcat = wcat; pp.zbf = zbf; pp.bias = bias; pp.wout = wout; pp.bout = bout;
  pp.h0 = h0; pp.h1 = h1; pp.out = out; pp.flags = flags;

  hipFuncSetAttribute((const void*)k_persist,
                      hipFuncAttributeMaxDynamicSharedMemorySize, SMEM_SZ);
  void* args[] = {&pp};
  hipError_t e = hipLaunchCooperativeKernel((const void*)k_persist, dim3(512), dim3(256),
                                            args, SMEM_SZ, stream);
  if (e == hipSuccess) return;

  for (int t = 0; t < TSTEP; ++t) {
    const unsigned short* hp = (t & 1) ? h0 : h1;
    unsigned short* hn = (t & 1) ? h1 : h0;
    if (t == 0)
      k_stepF<1, 0><<<dim3(512), dim3(256), 0, stream>>>(hp, hn, wcat, zbf, wout, bias,
                                                         bout, cst, out, t);
    else
      k_stepF<1, 1><<<dim3(512), dim3(256), 0, stream>>>(hp, hn, wcat, zbf, wout, bias,
                                                         bout, cst, out, t);
  }
  k_stepF<0, 1><<<dim3(32), dim3(256), 0, stream>>>(h1, h0, wcat, zbf, wout, bias,
                                                    bout, cst, out, TSTEP);
}

// Round 14
// 901.197 us; speedup vs baseline: 1.9671x; 1.0116x over previous
//
#include <hip/hip_runtime.h>

// LSTM decoder B=2048, Z=64, A=8, H=512, T=64.
// Round 14: r13 persistent kernel + pipelined cluster sync:
//  - per-pair flags: chunk kk of A needs only producers nt=2kk,2kk+1 ->
//    spin just-in-time per chunk instead of all-16 barrier per step.
//  - chunk rotation: WG nt starts at chunk c0=nt>>1 (own columns first,
//    staggers producer gating + spreads IF$ reads).
// vmcnt budgets position-identical to r13 (verified passing).
// Fallback: r9 multi-launch (926 us).

#define HID   512
#define TSTEP 64
#define KCAT  576

typedef unsigned long long u64;
typedef __attribute__((ext_vector_type(8))) short bf16x8;
typedef __attribute__((ext_vector_type(4))) float f32x4;

__device__ inline unsigned short f2bf(float f) {
  unsigned int u = __builtin_bit_cast(unsigned int, f);
  unsigned int r = (u + 0x7fffu + ((u >> 16) & 1u)) >> 16;
  return (unsigned short)r;
}
__device__ inline float sigm(float x) { return 1.0f / (1.0f + __expf(-x)); }
__device__ inline float tanh_f(float x) { return 1.0f - 2.0f / (__expf(2.0f * x) + 1.0f); }

__device__ inline void gl16(const unsigned short* g, unsigned short* l) {
  __builtin_amdgcn_global_load_lds(
      (const __attribute__((address_space(1))) unsigned int*)g,
      (__attribute__((address_space(3))) unsigned int*)l, 16, 0, 0);
}
// coherent 16B load (agent scope: bypasses L1 + non-coherent L2)
__device__ inline void ldc16(bf16x8& d, const unsigned short* p) {
  asm volatile("global_load_dwordx4 %0, %1, off sc0 sc1"
               : "=v"(d) : "v"(p) : "memory");
}

#define ATOMLD(PTR) __hip_atomic_load((PTR), __ATOMIC_RELAXED, __HIP_MEMORY_SCOPE_AGENT)
#define ATOMST(PTR, V) __hip_atomic_store((PTR), (V), __ATOMIC_RELAXED, __HIP_MEMORY_SCOPE_AGENT)
#define WAITV(N) do { asm volatile("s_waitcnt vmcnt(" #N ")" ::: "memory"); \
                      __builtin_amdgcn_sched_barrier(0); } while (0)

// ---- merged prep ----
__global__ void k_prep(const float* __restrict__ z, const float* __restrict__ wih,
                       const float* __restrict__ whh, const float* __restrict__ bih,
                       const float* __restrict__ bhh,
                       unsigned short* __restrict__ wcat, unsigned short* __restrict__ zbf,
                       float* __restrict__ bias) {
  int c = blockIdx.x * 256 + threadIdx.x;
  if (c < 147456) {
    int n = c / 72, kc = (c % 72) * 8;
    unsigned short u[8];
#pragma unroll
    for (int e = 0; e < 8; ++e) {
      int k = kc + e;
      float v = (k < 512) ? whh[(size_t)n * 512 + k] : wih[(size_t)n * 72 + 8 + (k - 512)];
      u[e] = f2bf(v);
    }
    *(bf16x8*)&wcat[(size_t)n * KCAT + kc] = *(bf16x8*)u;
  } else if (c < 163840) {
    int i = c - 147456;
    int row = i >> 3, kc = (i & 7) * 8;
    unsigned short u[8];
#pragma unroll
    for (int e = 0; e < 8; ++e) u[e] = f2bf(z[(size_t)row * 64 + kc + e]);
    *(bf16x8*)&zbf[(size_t)row * 64 + kc] = *(bf16x8*)u;
  } else if (c < 165888) {
    int n = c - 163840;
    bias[n] = bih[n] + bhh[n];
  }
}

__global__ void k_zero(int* __restrict__ flags) {
  int g = blockIdx.x * 256 + threadIdx.x;
  if (g < TSTEP * 512) flags[g] = 0;
}

struct P {
  const unsigned short *wcat, *zbf;
  const float *bias, *wout, *bout;
  unsigned short *h0, *h1;
  float* out;
  int* flags;
};

// LDS: Bb0 0 | Bb1 16384 | Bb2 32768 | wo 49152 | hO 65536 ; total 70656
#define SMEM_SZ 70656

__global__ __launch_bounds__(256, 2) void k_persist(P p) {
  extern __shared__ char smem[];
  unsigned short* Bb[3] = {(unsigned short*)smem, (unsigned short*)(smem + 16384),
                           (unsigned short*)(smem + 32768)};
  unsigned short* wo = (unsigned short*)(smem + 49152);
  unsigned short* hO = (unsigned short*)(smem + 65536);

  const int bid = blockIdx.x;
  const int nt = bid >> 5, bt = bid & 31;      // bid%8 == bt%8 (XCD-local cluster)
  const int tid = threadIdx.x;
  const int lane = tid & 63;
  const int wv = tid >> 6;
  const int mq = wv >> 1, nh = wv & 1;
  const int cl = lane & 15, q8 = lane >> 4;
  const int b0 = bt * 64, j0 = nt * 32;
  const int c0 = nt >> 1;                      // rotation start chunk (own pair)

  // ---- B staging (verified pattern) ----
  const int rS = tid >> 3;
  const int xS = ((tid & 7) ^ (rS & 7)) * 8;
  const unsigned short* srcB[4];
#pragma unroll
  for (int k = 0; k < 4; ++k) {
    int rB = k * 32 + rS;
    int n = (rB >> 5) * HID + j0 + (rB & 31);
    srcB[k] = p.wcat + (size_t)n * KCAT + xS;
  }
#define STAGEB(BUF, CHUNK) { _Pragma("unroll") for (int k4 = 0; k4 < 4; ++k4) \
    gl16(srcB[k4] + (CHUNK) * 64, &Bb[BUF][(k4 * 256 + wv * 64) * 8]); }

  // ---- one-time: W_out -> LDS (nt==0), z frags -> regs ----
  if (nt == 0) {
    int r = tid >> 4, s0 = tid & 15;
#pragma unroll
    for (int i = 0; i < 4; ++i) {
      int s = s0 + i * 16;
      unsigned short u[8] = {0, 0, 0, 0, 0, 0, 0, 0};
      if (r < 8) {
        const float* wp = p.wout + (size_t)r * 512 + s * 8;
        float4 f0 = *(const float4*)wp;
        float4 f1 = *(const float4*)(wp + 4);
        u[0] = f2bf(f0.x); u[1] = f2bf(f0.y); u[2] = f2bf(f0.z); u[3] = f2bf(f0.w);
        u[4] = f2bf(f1.x); u[5] = f2bf(f1.y); u[6] = f2bf(f1.z); u[7] = f2bf(f1.w);
      }
      int off = r * 512 + (s >> 3) * 64 + (((s & 7) ^ (r & 7)) * 8);
      *(bf16x8*)&wo[off] = *(bf16x8*)u;
    }
  }
  bf16x8 azr[4];
#pragma unroll
  for (int m = 0; m < 2; ++m)
#pragma unroll
    for (int ks = 0; ks < 2; ++ks)
      azr[m * 2 + ks] = *(const bf16x8*)&p.zbf[(size_t)(b0 + mq * 32 + m * 16 + cl) * 64 + ks * 32 + q8 * 8];

  // ---- persistent registers ----
  float bias_r[4];
#pragma unroll
  for (int g = 0; g < 4; ++g) bias_r[g] = p.bias[g * HID + j0 + nh * 16 + cl];
  f32x4 c0v = {0, 0, 0, 0}, c1v = {0, 0, 0, 0};
  f32x4 acc[4][2];
  f32x4 accp0, accp1;
  const float boutv = (cl < 8) ? p.bout[cl] : 0.0f;
  const int arow = tid >> 2, aseg = tid & 3;   // h store mapping
  const int r0 = b0 + mq * 32 + cl;

  bf16x8 ra[3][4];
  auto issueA = [&](bf16x8 d[4], const unsigned short* hp, int kk) {
    const unsigned short* base0 = hp + (size_t)r0 * HID + kk * 64 + q8 * 8;
    const unsigned short* base1 = base0 + 16 * HID;
    ldc16(d[0], base0);
    ldc16(d[1], base0 + 32);
    ldc16(d[2], base1);
    ldc16(d[3], base1 + 32);
  };

  auto gate_mfma = [&](const bf16x8 a4[4], const unsigned short* Bl, int kkv) {
    __builtin_amdgcn_s_setprio(1);
#pragma unroll
    for (int ks = 0; ks < 2; ++ks) {
      const int sx = ((ks * 4 + q8) ^ (cl & 7)) * 8;
      bf16x8 af0 = a4[ks], af1 = a4[2 + ks];
#pragma unroll
      for (int g = 0; g < 4; ++g) {
        bf16x8 bf = *(const bf16x8*)&Bl[(g * 32 + nh * 16 + cl) * 64 + sx];
        acc[g][0] = __builtin_amdgcn_mfma_f32_16x16x32_bf16(af0, bf, acc[g][0], 0, 0, 0);
        acc[g][1] = __builtin_amdgcn_mfma_f32_16x16x32_bf16(af1, bf, acc[g][1], 0, 0, 0);
      }
      if (nt == 0 && nh == 0 && kkv < 8) {
        bf16x8 wf = *(const bf16x8*)&wo[cl * 512 + kkv * 64 + sx];
        accp0 = __builtin_amdgcn_mfma_f32_16x16x32_bf16(af0, wf, accp0, 0, 0, 0);
        accp1 = __builtin_amdgcn_mfma_f32_16x16x32_bf16(af1, wf, accp1, 0, 0, 0);
      }
    }
    __builtin_amdgcn_s_setprio(0);
  };

  // cell + h store + cross-step B prefetch (rotated chunks c0, c0+1) + flag
  auto cell_store_flag = [&](unsigned short* hcur, int t) {
#pragma unroll
    for (int fm = 0; fm < 2; ++fm) {
      f32x4 cold = fm ? c1v : c0v;
      f32x4 cn;
#pragma unroll
      for (int r = 0; r < 4; ++r) {
        float iv = sigm(acc[0][fm][r]);
        float fv = sigm(acc[1][fm][r]);
        float gv = tanh_f(acc[2][fm][r]);
        float ov = sigm(acc[3][fm][r]);
        float cv = fv * cold[r] + iv * gv;
        cn[r] = cv;
        hO[(mq * 32 + fm * 16 + q8 * 4 + r) * 40 + nh * 16 + cl] = f2bf(ov * tanh_f(cv));
      }
      if (fm) c1v = cn; else c0v = cn;
    }
    __syncthreads();                            // hO ready; all waves past MFMA(z)
    u64 u0 = *(const u64*)&hO[arow * 40 + aseg * 8];
    u64 u1 = *(const u64*)&hO[arow * 40 + aseg * 8 + 4];
    u64* dst = (u64*)(hcur + (size_t)(b0 + arow) * HID + j0 + aseg * 8);
    ATOMST(dst, u0);
    ATOMST(dst + 1, u1);
    STAGEB(0, c0);                              // next-step W prefetch (rotated)
    STAGEB(1, (c0 + 1) & 7);
    WAITV(8);                                   // own h stores complete; B may fly
    __builtin_amdgcn_s_barrier();               // everyone's h stores complete
    if (tid == 0)
      ATOMST(&p.flags[t * 512 + bt * 16 + nt], 1);
  };

  // ================= t = 0 : z-chunk only =================
  STAGEB(2, 8);
  asm volatile("s_waitcnt vmcnt(0) lgkmcnt(0)" ::: "memory");
  __builtin_amdgcn_sched_barrier(0);
  __builtin_amdgcn_s_barrier();
#pragma unroll
  for (int g = 0; g < 4; ++g) {
    f32x4 v = {bias_r[g], bias_r[g], bias_r[g], bias_r[g]};
    acc[g][0] = v; acc[g][1] = v;
  }
  gate_mfma(azr, Bb[2], 8);
  cell_store_flag(p.h0, 0);

  // ================= t = 1 .. 63 =================
  for (int t = 1; t < TSTEP; ++t) {
    const unsigned short* hprev = (t & 1) ? p.h0 : p.h1;
    unsigned short* hcur = (t & 1) ? p.h1 : p.h0;
    const int* fbase = &p.flags[(t - 1) * 512 + bt * 16];

    // prologue: wait producers of rotated chunks c0..c0+3 (chunks used at
    // phases 0..2 A-prefetch + phase-0 in-loop issue of rc(3))
    if (tid < 8) {
      int rcq = (c0 + (tid >> 1)) & 7;
      const int* fp = fbase + rcq * 2 + (tid & 1);
      while (ATOMLD(fp) == 0) __builtin_amdgcn_s_sleep(1);
    }
    __syncthreads();

    issueA(ra[0], hprev, c0);
    issueA(ra[1], hprev, (c0 + 1) & 7);
    issueA(ra[2], hprev, (c0 + 2) & 7);
    WAITV(8);                                   // retires B(rc0),B(rc1),A(rc0)
    __builtin_amdgcn_s_barrier();

#pragma unroll
    for (int g = 0; g < 4; ++g) {
      f32x4 v = {bias_r[g], bias_r[g], bias_r[g], bias_r[g]};
      acc[g][0] = v; acc[g][1] = v;
    }
    { f32x4 v = {boutv, boutv, boutv, boutv}; accp0 = v; accp1 = v; }

#pragma unroll
    for (int j = 0; j <= 8; ++j) {
      const int rcj = (c0 + j) & 7;             // real chunk at phase j (j<8)
      gate_mfma(j < 8 ? ra[j % 3] : azr, Bb[j % 3], j < 8 ? rcj : 8);
      if (j == 8) break;
      if (j <= 4) issueA(ra[j % 3], hprev, (c0 + j + 3) & 7);
      if (j <= 6) STAGEB((j + 2) % 3, (j + 2 < 8) ? ((c0 + j + 2) & 7) : 8);
      if (j <= 3 && tid < 2) {                  // JIT spin: producers of rc(j+4)
        const int* fp = fbase + ((c0 + j + 4) & 7) * 2 + tid;
        while (ATOMLD(fp) == 0) __builtin_amdgcn_s_sleep(1);
      }
      // budgets identical to r13 (position-verified)
      if (j == 0)      WAITV(12);
      else if (j <= 4) WAITV(8);
      else if (j <= 6) WAITV(4);
      else             WAITV(0);
      __builtin_amdgcn_s_barrier();
    }

    if (nt == 0 && nh == 0 && cl < 8) {
      const int tt = t - 1;
#pragma unroll
      for (int r = 0; r < 4; ++r) {
        int b = b0 + mq * 32 + q8 * 4 + r;
        p.out[((size_t)b * 64 + tt) * 8 + cl] = accp0[r];
        p.out[((size_t)(b + 16) * 64 + tt) * 8 + cl] = accp1[r];
      }
    }
    cell_store_flag(hcur, t);
  }

  // ================= epilogue: projection of h(63), nt==0 WGs =================
  if (nt == 0) {
    if (tid < 16) {
      const int* fp = &p.flags[63 * 512 + bt * 16 + tid];
      while (ATOMLD(fp) == 0) __builtin_amdgcn_s_sleep(1);
    }
    __syncthreads();
    const unsigned short* h63 = p.h1;           // t=63 wrote h1
    issueA(ra[0], h63, 0);
    issueA(ra[1], h63, 1);
    issueA(ra[2], h63, 2);
    f32x4 ap0 = {boutv, boutv, boutv, boutv};
    f32x4 ap1 = ap0;
#pragma unroll
    for (int kk = 0; kk < 8; ++kk) {
      if (kk <= 5)      WAITV(8);
      else if (kk == 6) WAITV(4);
      else              WAITV(0);
      if (nh == 0) {
#pragma unroll
        for (int ks = 0; ks < 2; ++ks) {
          const int sx = ((ks * 4 + q8) ^ (cl & 7)) * 8;
          bf16x8 wf = *(const bf16x8*)&wo[cl * 512 + kk * 64 + sx];
          ap0 = __builtin_amdgcn_mfma_f32_16x16x32_bf16(ra[kk % 3][ks], wf, ap0, 0, 0, 0);
          ap1 = __builtin_amdgcn_mfma_f32_16x16x32_bf16(ra[kk % 3][2 + ks], wf, ap1, 0, 0, 0);
        }
      }
      if (kk <= 4) issueA(ra[kk % 3], h63, kk + 3);
    }
    if (nh == 0 && cl < 8) {
#pragma unroll
      for (int r = 0; r < 4; ++r) {
        int b = b0 + mq * 32 + q8 * 4 + r;
        p.out[((size_t)b * 64 + 63) * 8 + cl] = ap0[r];
        p.out[((size_t)(b + 16) * 64 + 63) * 8 + cl] = ap1[r];
      }
    }
  }
#undef STAGEB
}

// ================= fallback: round-9 multi-launch (passed @926us) =================
template <int GATES, int PROJ>
__global__ __launch_bounds__(256, 2) void k_stepF(
    const unsigned short* __restrict__ hprev, unsigned short* __restrict__ hnext,
    const unsigned short* __restrict__ wcat, const unsigned short* __restrict__ zbf,
    const float* __restrict__ wout, const float* __restrict__ bias,
    const float* __restrict__ bout, float* __restrict__ cst,
    float* __restrict__ out, int t) {
  __shared__ unsigned short Ab[2][64 * 64];
  __shared__ unsigned short Bb[2][128 * 64];
  __shared__ unsigned short wo_lds[16 * 512];
  __shared__ unsigned short hO[64 * 40];

  const int bid = blockIdx.x;
  const int nt = GATES ? (((bid & 7) << 1) | ((bid >> 8) & 1)) : 0;
  const int bt = GATES ? ((bid >> 3) & 31) : bid;
  const int tid = threadIdx.x;
  const int lane = tid & 63;
  const int wv = tid >> 6;
  const int mq = wv >> 1, nh = wv & 1;
  const int cl = lane & 15, q8 = lane >> 4;
  const int b0 = bt * 64, j0 = nt * 32;

  const int rA = tid >> 3;
  const int xA = ((tid & 7) ^ (rA & 7)) * 8;
  const unsigned short* srcA0 = hprev + (size_t)(b0 + rA) * HID + xA;
  const unsigned short* srcA1 = hprev + (size_t)(b0 + 32 + rA) * HID + xA;
  const unsigned short* srcZ0 = zbf + (size_t)(b0 + rA) * 64 + xA;
  const unsigned short* srcZ1 = zbf + (size_t)(b0 + 32 + rA) * 64 + xA;
  const unsigned short* srcB[4];
#pragma unroll
  for (int k = 0; k < 4; ++k) {
    int rB = k * 32 + rA;
    int n = (rB >> 5) * HID + j0 + (rB & 31);
    srcB[k] = wcat + (size_t)n * KCAT + xA;
  }

  auto do_stage = [&](int buf, int kkv) {
    if (GATES) {
      if (kkv == 8) {
        gl16(srcZ0, &Ab[buf][(wv * 64) * 8]);
        gl16(srcZ1, &Ab[buf][(256 + wv * 64) * 8]);
      } else {
        gl16(srcA0 + kkv * 64, &Ab[buf][(wv * 64) * 8]);
        gl16(srcA1 + kkv * 64, &Ab[buf][(256 + wv * 64) * 8]);
      }
#pragma unroll
      for (int k = 0; k < 4; ++k)
        gl16(srcB[k] + kkv * 64, &Bb[buf][(k * 256 + wv * 64) * 8]);
    } else {
      gl16(srcA0 + kkv * 64, &Ab[buf][(wv * 64) * 8]);
      gl16(srcA1 + kkv * 64, &Ab[buf][(256 + wv * 64) * 8]);
    }
  };

  if (PROJ) {
    int r = tid >> 4, s0 = tid & 15;
#pragma unroll
    for (int i = 0; i < 4; ++i) {
      int s = s0 + i * 16;
      unsigned short u[8] = {0, 0, 0, 0, 0, 0, 0, 0};
      if (r < 8) {
        const float* wp = wout + (size_t)r * 512 + s * 8;
        float4 f0 = *(const float4*)wp;
        float4 f1 = *(const float4*)(wp + 4);
        u[0] = f2bf(f0.x); u[1] = f2bf(f0.y); u[2] = f2bf(f0.z); u[3] = f2bf(f0.w);
        u[4] = f2bf(f1.x); u[5] = f2bf(f1.y); u[6] = f2bf(f1.z); u[7] = f2bf(f1.w);
      }
      int off = r * 512 + (s >> 3) * 64 + (((s & 7) ^ (r & 7)) * 8);
      *(bf16x8*)&wo_lds[off] = *(bf16x8*)u;
    }
  }

  f32x4 acc[4][2];
  if (GATES) {
#pragma unroll
    for (int g = 0; g < 4; ++g) {
      float bv = bias[g * HID + j0 + nh * 16 + cl];
      f32x4 v = {bv, bv, bv, bv};
      acc[g][0] = v; acc[g][1] = v;
    }
  }
  f32x4 accp0 = {0, 0, 0, 0}, accp1 = {0, 0, 0, 0};
  if (PROJ) {
    float bo = (cl < 8) ? bout[cl] : 0.0f;
    f32x4 v = {bo, bo, bo, bo};
    accp0 = v; accp1 = v;
  }

  const size_t cbase = ((size_t)bid * 256 + tid) * 8;
  f32x4 c0 = {0, 0, 0, 0}, c1 = {0, 0, 0, 0};
  if (GATES && t > 0) { c0 = *(const f32x4*)&cst[cbase]; c1 = *(const f32x4*)&cst[cbase + 4]; }

  auto mfma_block = [&](int bu, int kkv) {
    const unsigned short* Al = Ab[bu];
    const unsigned short* Bl = Bb[bu];
#pragma unroll
    for (int ks = 0; ks < 2; ++ks) {
      const int sx = ((ks * 4 + q8) ^ (cl & 7)) * 8;
      bf16x8 af0 = *(const bf16x8*)&Al[(mq * 32 + cl) * 64 + sx];
      bf16x8 af1 = *(const bf16x8*)&Al[(mq * 32 + 16 + cl) * 64 + sx];
      if (GATES) {
#pragma unroll
        for (int g = 0; g < 4; ++g) {
          bf16x8 bf = *(const bf16x8*)&Bl[(g * 32 + nh * 16 + cl) * 64 + sx];
          acc[g][0] = __builtin_amdgcn_mfma_f32_16x16x32_bf16(af0, bf, acc[g][0], 0, 0, 0);
          acc[g][1] = __builtin_amdgcn_mfma_f32_16x16x32_bf16(af1, bf, acc[g][1], 0, 0, 0);
        }
      }
      if (PROJ && nh == 0 && kkv < 8) {
        bf16x8 wf = *(const bf16x8*)&wo_lds[cl * 512 + kkv * 64 + sx];
        accp0 = __builtin_amdgcn_mfma_f32_16x16x32_bf16(af0, wf, accp0, 0, 0, 0);
        accp1 = __builtin_amdgcn_mfma_f32_16x16x32_bf16(af1, wf, accp1, 0, 0, 0);
      }
    }
  };

  if (GATES && t == 0) {
    do_stage(0, 8);
    asm volatile("s_waitcnt vmcnt(0) lgkmcnt(0)" ::: "memory");
    __builtin_amdgcn_s_barrier();
    mfma_block(0, 8);
  } else {
    do_stage(0, 0);
    do_stage(1, 1);
    if (GATES) asm volatile("s_waitcnt vmcnt(6) lgkmcnt(0)" ::: "memory");
    else       asm volatile("s_waitcnt vmcnt(2) lgkmcnt(0)" ::: "memory");
    __builtin_amdgcn_s_barrier();
    const int kkEnd = GATES ? 8 : 7;
    for (int kk = 0;; ++kk) {
      mfma_block(kk & 1, kk);
      if (kk == kkEnd) break;
      asm volatile("" ::: "memory");
      __builtin_amdgcn_s_barrier();
      if (kk + 2 <= kkEnd) {
        do_stage(kk & 1, kk + 2);
        if (GATES) asm volatile("s_waitcnt vmcnt(6)" ::: "memory");
        else       asm volatile("s_waitcnt vmcnt(2)" ::: "memory");
      } else {
        asm volatile("s_waitcnt vmcnt(0)" ::: "memory");
      }
      asm volatile("" ::: "memory");
      __builtin_amdgcn_s_barrier();
    }
  }

  if (PROJ && nh == 0 && cl < 8) {
    const int tt = t - 1;
#pragma unroll
    for (int r = 0; r < 4; ++r) {
      int b = b0 + mq * 32 + q8 * 4 + r;
      out[((size_t)b * 64 + tt) * 8 + cl] = accp0[r];
      out[((size_t)(b + 16) * 64 + tt) * 8 + cl] = accp1[r];
    }
  }

  if (GATES) {
#pragma unroll
    for (int fm = 0; fm < 2; ++fm) {
      f32x4 cold = fm ? c1 : c0;
      f32x4 cn;
#pragma unroll
      for (int r = 0; r < 4; ++r) {
        float iv = sigm(acc[0][fm][r]);
        float fv = sigm(acc[1][fm][r]);
        float gv = tanh_f(acc[2][fm][r]);
        float ov = sigm(acc[3][fm][r]);
        float cv = fv * cold[r] + iv * gv;
        cn[r] = cv;
        hO[(mq * 32 + fm * 16 + q8 * 4 + r) * 40 + nh * 16 + cl] = f2bf(ov * tanh_f(cv));
      }
      if (fm) c1 = cn; else c0 = cn;
    }
    *(f32x4*)&cst[cbase] = c0;
    *(f32x4*)&cst[cbase + 4] = c1;
    __syncthreads();
    int row = tid >> 2, sg4 = tid & 3;
    unsigned short tmp[8];
#pragma unroll
    for (int e = 0; e < 8; ++e) tmp[e] = hO[row * 40 + sg4 * 8 + e];
    *(int4*)&hnext[(size_t)(b0 + row) * HID + j0 + sg4 * 8] = *(int4*)tmp;
  }
}

extern "C" void kernel_launch(void* const* d_in, const int* in_sizes, int n_in,
                              void* d_out, int out_size, void* d_ws, size_t ws_size,
                              hipStream_t stream) {
  const float* z    = (const float*)d_in[0];
  const float* wih  = (const float*)d_in[1];
  const float* whh  = (const float*)d_in[2];
  const float* bih  = (const float*)d_in[3];
  const float* bhh  = (const float*)d_in[4];
  const float* wout = (const float*)d_in[5];
  const float* bout = (const float*)d_in[6];
  float* out = (float*)d_out;

  char* ws = (char*)d_ws;
  unsigned short* wcat = (unsigned short*)(ws);              // 2,359,296
  unsigned short* zbf  = (unsigned short*)(ws + 2359296);    //   262,144
  float* bias          = (float*)(ws + 2621440);             //     8,192
  unsigned short* h0   = (unsigned short*)(ws + 2629632);    // 2,097,152
  unsigned short* h1   = (unsigned short*)(ws + 4726784);    // 2,097,152
  int* flags           = (int*)(ws + 6823936);               //   131,072
  float* cst           = (float*)(ws + 6955008);             // 4,194,304 (fallback)

  k_prep<<<dim3(648), dim3(256), 0, stream>>>(z, wih, whh, bih, bhh, wcat, zbf, bias);
  k_zero<<<dim3(128), dim3(256), 0, stream>>>(flags);

  P pp;
  pp.wcat = wcat; pp.zbf = zbf; pp.bias = bias; pp.wout = wout; pp.bout = bout;
  pp.h0 = h0; pp.h1 = h1; pp.out = out; pp.flags = flags;

  hipFuncSetAttribute((const void*)k_persist,
                      hipFuncAttributeMaxDynamicSharedMemorySize, SMEM_SZ);
  void* args[] = {&pp};
  hipError_t e = hipLaunchCooperativeKernel((const void*)k_persist, dim3(512), dim3(256),
                                            args, SMEM_SZ, stream);
  if (e == hipSuccess) return;

  for (int t = 0; t < TSTEP; ++t) {
    const unsigned short* hp = (t & 1) ? h0 : h1;
    unsigned short* hn = (t & 1) ? h1 : h0;
    if (t == 0)
      k_stepF<1, 0><<<dim3(512), dim3(256), 0, stream>>>(hp, hn, wcat, zbf, wout, bias,
                                                         bout, cst, out, t);
    else
      k_stepF<1, 1><<<dim3(512), dim3(256), 0, stream>>>(hp, hn, wcat, zbf, wout, bias,
                                                         bout, cst, out, t);
  }
  k_stepF<0, 1><<<dim3(32), dim3(256), 0, stream>>>(h1, h0, wcat, zbf, wout, bias,
                                                    bout, cst, out, TSTEP);
}

// Round 16
// 784.662 us; speedup vs baseline: 2.2593x; 1.1485x over previous
//
#include <hip/hip_runtime.h>

// LSTM decoder B=2048, Z=64, A=8, H=512, T=64.
// Round 15b: (r15 with compile fix — stray "acc p0;" removed).
// Persistent cooperative kernel, W RESIDENT in LDS (9x16KB planes,
// filled once), barrier-free K-loop: A (h) -> regs via coherent 16B loads
// (4-deep, per-wave counted vmcnt), B from immutable LDS, W_out in registers.
// 256 WGs x 512 thr (8 waves, 2/SIMD). Flag sync as r13/14 (verified).
// Fallback: r9 multi-launch (926 us).

#define HID   512
#define TSTEP 64
#define KCAT  576

typedef unsigned long long u64;
typedef __attribute__((ext_vector_type(8))) short bf16x8;
typedef __attribute__((ext_vector_type(4))) float f32x4;

__device__ inline unsigned short f2bf(float f) {
  unsigned int u = __builtin_bit_cast(unsigned int, f);
  unsigned int r = (u + 0x7fffu + ((u >> 16) & 1u)) >> 16;
  return (unsigned short)r;
}
__device__ inline float sigm(float x) { return 1.0f / (1.0f + __expf(-x)); }
__device__ inline float tanh_f(float x) { return 1.0f - 2.0f / (__expf(2.0f * x) + 1.0f); }

__device__ inline void gl16(const unsigned short* g, unsigned short* l) {
  __builtin_amdgcn_global_load_lds(
      (const __attribute__((address_space(1))) unsigned int*)g,
      (__attribute__((address_space(3))) unsigned int*)l, 16, 0, 0);
}
// coherent 16B load (agent scope: bypasses L1 + non-coherent L2)
__device__ inline void ldc16(bf16x8& d, const unsigned short* p) {
  asm volatile("global_load_dwordx4 %0, %1, off sc0 sc1"
               : "=v"(d) : "v"(p) : "memory");
}

#define ATOMLD(PTR) __hip_atomic_load((PTR), __ATOMIC_RELAXED, __HIP_MEMORY_SCOPE_AGENT)
#define ATOMST(PTR, V) __hip_atomic_store((PTR), (V), __ATOMIC_RELAXED, __HIP_MEMORY_SCOPE_AGENT)
#define WAITV(N) do { asm volatile("s_waitcnt vmcnt(" #N ")" ::: "memory"); \
                      __builtin_amdgcn_sched_barrier(0); } while (0)

// ---- merged prep ----
__global__ void k_prep(const float* __restrict__ z, const float* __restrict__ wih,
                       const float* __restrict__ whh, const float* __restrict__ bih,
                       const float* __restrict__ bhh,
                       unsigned short* __restrict__ wcat, unsigned short* __restrict__ zbf,
                       float* __restrict__ bias) {
  int c = blockIdx.x * 256 + threadIdx.x;
  if (c < 147456) {
    int n = c / 72, kc = (c % 72) * 8;
    unsigned short u[8];
#pragma unroll
    for (int e = 0; e < 8; ++e) {
      int k = kc + e;
      float v = (k < 512) ? whh[(size_t)n * 512 + k] : wih[(size_t)n * 72 + 8 + (k - 512)];
      u[e] = f2bf(v);
    }
    *(bf16x8*)&wcat[(size_t)n * KCAT + kc] = *(bf16x8*)u;
  } else if (c < 163840) {
    int i = c - 147456;
    int row = i >> 3, kc = (i & 7) * 8;
    unsigned short u[8];
#pragma unroll
    for (int e = 0; e < 8; ++e) u[e] = f2bf(z[(size_t)row * 64 + kc + e]);
    *(bf16x8*)&zbf[(size_t)row * 64 + kc] = *(bf16x8*)u;
  } else if (c < 165888) {
    int n = c - 163840;
    bias[n] = bih[n] + bhh[n];
  }
}

__global__ void k_zero(int* __restrict__ flags) {
  int g = blockIdx.x * 256 + threadIdx.x;
  if (g < TSTEP * 256) flags[g] = 0;
}

struct P {
  const unsigned short *wcat, *zbf;
  const float *bias, *wout, *bout;
  unsigned short *h0, *h1;
  float* out;
  int* flags;
};

// LDS: W planes kk=0..8 at kk*16384 (147456 B) | hO at 147456 (10240 B)
#define SMEM_SZ 157696

__global__ __launch_bounds__(512, 2) void k_persist(P p) {
  extern __shared__ char smem[];
#define WPL(KK) ((unsigned short*)(smem + (KK) * 16384))
  unsigned short* hO = (unsigned short*)(smem + 147456);

  const int bid = blockIdx.x;
  const int nt = bid >> 4, bt = bid & 15;
  const int tid = threadIdx.x;
  const int lane = tid & 63;
  const int wv = tid >> 6;                     // 0..7
  const int mq = wv >> 1, nh = wv & 1;
  const int cl = lane & 15, q8 = lane >> 4;
  const int b0 = bt * 128, j0 = nt * 32;
  const int c0 = (nt == 0) ? 0 : (nt >> 1);    // rotation (nt==0 fixed: wfr idx)

  // ---- fill W planes once (verified staged layout, 2 slots x 9 chunks) ----
  {
    const int rS = tid >> 3;                   // 0..63
    const int xS = ((tid & 7) ^ (rS & 7)) * 8;
    int n0 = (rS >> 5) * HID + j0 + (rS & 31);
    int n1 = ((rS + 64) >> 5) * HID + j0 + ((rS + 64) & 31);
    const unsigned short* s0 = p.wcat + (size_t)n0 * KCAT + xS;
    const unsigned short* s1 = p.wcat + (size_t)n1 * KCAT + xS;
#pragma unroll
    for (int kk = 0; kk < 9; ++kk) {
      gl16(s0 + kk * 64, &WPL(kk)[(wv * 64) * 8]);
      gl16(s1 + kk * 64, &WPL(kk)[(512 + wv * 64) * 8]);
    }
  }

  // ---- W_out fragments in registers (nt==0, nh==0 waves; rows>=8 zero) ----
  bf16x8 wfr[8][2];
  if (nt == 0 && nh == 0) {
#pragma unroll
    for (int kk = 0; kk < 8; ++kk)
#pragma unroll
      for (int ks = 0; ks < 2; ++ks) {
        unsigned short u[8] = {0, 0, 0, 0, 0, 0, 0, 0};
        if (cl < 8) {
          const float* wp = p.wout + (size_t)cl * 512 + kk * 64 + ks * 32 + q8 * 8;
          float4 f0 = *(const float4*)wp;
          float4 f1 = *(const float4*)(wp + 4);
          u[0] = f2bf(f0.x); u[1] = f2bf(f0.y); u[2] = f2bf(f0.z); u[3] = f2bf(f0.w);
          u[4] = f2bf(f1.x); u[5] = f2bf(f1.y); u[6] = f2bf(f1.z); u[7] = f2bf(f1.w);
        }
        wfr[kk][ks] = *(bf16x8*)u;
      }
  }

  // ---- z fragments, bias, c-state in registers ----
  bf16x8 azr[4];
#pragma unroll
  for (int m = 0; m < 2; ++m)
#pragma unroll
    for (int ks = 0; ks < 2; ++ks)
      azr[m * 2 + ks] = *(const bf16x8*)&p.zbf[(size_t)(b0 + mq * 32 + m * 16 + cl) * 64 + ks * 32 + q8 * 8];
  float bias_r[4];
#pragma unroll
  for (int g = 0; g < 4; ++g) bias_r[g] = p.bias[g * HID + j0 + nh * 16 + cl];
  f32x4 c0v = {0, 0, 0, 0}, c1v = {0, 0, 0, 0};
  f32x4 acc[4][2];
  f32x4 accp0, accp1;
  const float boutv = (cl < 8) ? p.bout[cl] : 0.0f;
  const int arow = tid >> 2, aseg = tid & 3;   // h store gather mapping
  const int r0 = b0 + mq * 32 + cl;

  bf16x8 ra[4][4];
  auto issueA = [&](bf16x8 d[4], const unsigned short* hp, int kk) {
    const unsigned short* base0 = hp + (size_t)r0 * HID + kk * 64 + q8 * 8;
    const unsigned short* base1 = base0 + 16 * HID;
    ldc16(d[0], base0);
    ldc16(d[1], base0 + 32);
    ldc16(d[2], base1);
    ldc16(d[3], base1 + 32);
  };

  // jph: compile-time phase (== real chunk for nt==0); isz: z chunk
  auto gate_mfma = [&](const bf16x8 a4[4], const unsigned short* Bl, int jph, bool isz) {
    __builtin_amdgcn_s_setprio(1);
#pragma unroll
    for (int ks = 0; ks < 2; ++ks) {
      const int sx = ((ks * 4 + q8) ^ (cl & 7)) * 8;
      bf16x8 af0 = a4[ks], af1 = a4[2 + ks];
#pragma unroll
      for (int g = 0; g < 4; ++g) {
        bf16x8 bf = *(const bf16x8*)&Bl[(g * 32 + nh * 16 + cl) * 64 + sx];
        acc[g][0] = __builtin_amdgcn_mfma_f32_16x16x32_bf16(af0, bf, acc[g][0], 0, 0, 0);
        acc[g][1] = __builtin_amdgcn_mfma_f32_16x16x32_bf16(af1, bf, acc[g][1], 0, 0, 0);
      }
      if (nt == 0 && nh == 0 && !isz) {
        accp0 = __builtin_amdgcn_mfma_f32_16x16x32_bf16(af0, wfr[jph][ks], accp0, 0, 0, 0);
        accp1 = __builtin_amdgcn_mfma_f32_16x16x32_bf16(af1, wfr[jph][ks], accp1, 0, 0, 0);
      }
    }
    __builtin_amdgcn_s_setprio(0);
  };

  auto cell_store_flag = [&](unsigned short* hcur, int t) {
#pragma unroll
    for (int fm = 0; fm < 2; ++fm) {
      f32x4 cold = fm ? c1v : c0v;
      f32x4 cn;
#pragma unroll
      for (int r = 0; r < 4; ++r) {
        float iv = sigm(acc[0][fm][r]);
        float fv = sigm(acc[1][fm][r]);
        float gv = tanh_f(acc[2][fm][r]);
        float ov = sigm(acc[3][fm][r]);
        float cv = fv * cold[r] + iv * gv;
        cn[r] = cv;
        hO[(mq * 32 + fm * 16 + q8 * 4 + r) * 40 + nh * 16 + cl] = f2bf(ov * tanh_f(cv));
      }
      if (fm) c1v = cn; else c0v = cn;
    }
    __syncthreads();                           // hO ready
    u64 u0 = *(const u64*)&hO[arow * 40 + aseg * 8];
    u64 u1 = *(const u64*)&hO[arow * 40 + aseg * 8 + 4];
    u64* dst = (u64*)(hcur + (size_t)(b0 + arow) * HID + j0 + aseg * 8);
    ATOMST(dst, u0);
    ATOMST(dst + 1, u1);
    WAITV(0);                                  // own stores complete
    __builtin_amdgcn_s_barrier();              // everyone's stores complete
    if (tid == 0)
      ATOMST(&p.flags[t * 256 + bt * 16 + nt], 1);
  };

  // ================= t = 0 : z-chunk only =================
  asm volatile("s_waitcnt vmcnt(0) lgkmcnt(0)" ::: "memory");
  __builtin_amdgcn_sched_barrier(0);
  __builtin_amdgcn_s_barrier();                // W planes resident
#pragma unroll
  for (int g = 0; g < 4; ++g) {
    f32x4 v = {bias_r[g], bias_r[g], bias_r[g], bias_r[g]};
    acc[g][0] = v; acc[g][1] = v;
  }
  gate_mfma(azr, WPL(8), 0, true);
  cell_store_flag(p.h0, 0);

  // ================= t = 1 .. 63 =================
  for (int t = 1; t < TSTEP; ++t) {
    const unsigned short* hprev = (t & 1) ? p.h0 : p.h1;
    unsigned short* hcur = (t & 1) ? p.h1 : p.h0;
    if (tid < 16) {
      const int* fp = &p.flags[(t - 1) * 256 + bt * 16 + tid];
      while (ATOMLD(fp) == 0) __builtin_amdgcn_s_sleep(1);
    }
    __syncthreads();

    issueA(ra[0], hprev, c0);
    issueA(ra[1], hprev, (c0 + 1) & 7);
    issueA(ra[2], hprev, (c0 + 2) & 7);
    issueA(ra[3], hprev, (c0 + 3) & 7);

#pragma unroll
    for (int g = 0; g < 4; ++g) {
      f32x4 v = {bias_r[g], bias_r[g], bias_r[g], bias_r[g]};
      acc[g][0] = v; acc[g][1] = v;
    }
    { f32x4 v = {boutv, boutv, boutv, boutv}; accp0 = v; accp1 = v; }

    // barrier-free K-loop: per-wave counted vmcnt only
#pragma unroll
    for (int j = 0; j <= 8; ++j) {
      if (j <= 4)      WAITV(12);
      else if (j == 5) WAITV(8);
      else if (j == 6) WAITV(4);
      else if (j == 7) WAITV(0);
      const unsigned short* Bl = (j < 8) ? WPL((c0 + j) & 7) : WPL(8);
      gate_mfma(j < 8 ? ra[j & 3] : azr, Bl, j < 8 ? j : 0, j == 8);
      if (j <= 3) issueA(ra[j & 3], hprev, (c0 + j + 4) & 7);
    }

    if (nt == 0 && nh == 0 && cl < 8) {
      const int tt = t - 1;
#pragma unroll
      for (int r = 0; r < 4; ++r) {
        int b = b0 + mq * 32 + q8 * 4 + r;
        p.out[((size_t)b * 64 + tt) * 8 + cl] = accp0[r];
        p.out[((size_t)(b + 16) * 64 + tt) * 8 + cl] = accp1[r];
      }
    }
    cell_store_flag(hcur, t);
  }

  // ================= epilogue: projection of h(63), nt==0 =================
  if (nt == 0) {
    if (tid < 16) {
      const int* fp = &p.flags[63 * 256 + bt * 16 + tid];
      while (ATOMLD(fp) == 0) __builtin_amdgcn_s_sleep(1);
    }
    __syncthreads();
    const unsigned short* h63 = p.h1;          // t=63 wrote h1
    f32x4 ap0 = {boutv, boutv, boutv, boutv};
    f32x4 ap1 = ap0;
    if (nh == 0) {
      issueA(ra[0], h63, 0);
      issueA(ra[1], h63, 1);
      issueA(ra[2], h63, 2);
      issueA(ra[3], h63, 3);
#pragma unroll
      for (int kk = 0; kk < 8; ++kk) {
        if (kk <= 4)      WAITV(12);
        else if (kk == 5) WAITV(8);
        else if (kk == 6) WAITV(4);
        else              WAITV(0);
#pragma unroll
        for (int ks = 0; ks < 2; ++ks) {
          ap0 = __builtin_amdgcn_mfma_f32_16x16x32_bf16(ra[kk & 3][ks], wfr[kk][ks], ap0, 0, 0, 0);
          ap1 = __builtin_amdgcn_mfma_f32_16x16x32_bf16(ra[kk & 3][2 + ks], wfr[kk][ks], ap1, 0, 0, 0);
        }
        if (kk <= 3) issueA(ra[kk & 3], h63, kk + 4);
      }
      if (cl < 8) {
#pragma unroll
        for (int r = 0; r < 4; ++r) {
          int b = b0 + mq * 32 + q8 * 4 + r;
          p.out[((size_t)b * 64 + 63) * 8 + cl] = ap0[r];
          p.out[((size_t)(b + 16) * 64 + 63) * 8 + cl] = ap1[r];
        }
      }
    }
  }
#undef WPL
}

// ================= fallback: round-9 multi-launch (passed @926us) =================
template <int GATES, int PROJ>
__global__ __launch_bounds__(256, 2) void k_stepF(
    const unsigned short* __restrict__ hprev, unsigned short* __restrict__ hnext,
    const unsigned short* __restrict__ wcat, const unsigned short* __restrict__ zbf,
    const float* __restrict__ wout, const float* __restrict__ bias,
    const float* __restrict__ bout, float* __restrict__ cst,
    float* __restrict__ out, int t) {
  __shared__ unsigned short Ab[2][64 * 64];
  __shared__ unsigned short Bb[2][128 * 64];
  __shared__ unsigned short wo_lds[16 * 512];
  __shared__ unsigned short hO[64 * 40];

  const int bid = blockIdx.x;
  const int nt = GATES ? (((bid & 7) << 1) | ((bid >> 8) & 1)) : 0;
  const int bt = GATES ? ((bid >> 3) & 31) : bid;
  const int tid = threadIdx.x;
  const int lane = tid & 63;
  const int wv = tid >> 6;
  const int mq = wv >> 1, nh = wv & 1;
  const int cl = lane & 15, q8 = lane >> 4;
  const int b0 = bt * 64, j0 = nt * 32;

  const int rA = tid >> 3;
  const int xA = ((tid & 7) ^ (rA & 7)) * 8;
  const unsigned short* srcA0 = hprev + (size_t)(b0 + rA) * HID + xA;
  const unsigned short* srcA1 = hprev + (size_t)(b0 + 32 + rA) * HID + xA;
  const unsigned short* srcZ0 = zbf + (size_t)(b0 + rA) * 64 + xA;
  const unsigned short* srcZ1 = zbf + (size_t)(b0 + 32 + rA) * 64 + xA;
  const unsigned short* srcB[4];
#pragma unroll
  for (int k = 0; k < 4; ++k) {
    int rB = k * 32 + rA;
    int n = (rB >> 5) * HID + j0 + (rB & 31);
    srcB[k] = wcat + (size_t)n * KCAT + xA;
  }

  auto do_stage = [&](int buf, int kkv) {
    if (GATES) {
      if (kkv == 8) {
        gl16(srcZ0, &Ab[buf][(wv * 64) * 8]);
        gl16(srcZ1, &Ab[buf][(256 + wv * 64) * 8]);
      } else {
        gl16(srcA0 + kkv * 64, &Ab[buf][(wv * 64) * 8]);
        gl16(srcA1 + kkv * 64, &Ab[buf][(256 + wv * 64) * 8]);
      }
#pragma unroll
      for (int k = 0; k < 4; ++k)
        gl16(srcB[k] + kkv * 64, &Bb[buf][(k * 256 + wv * 64) * 8]);
    } else {
      gl16(srcA0 + kkv * 64, &Ab[buf][(wv * 64) * 8]);
      gl16(srcA1 + kkv * 64, &Ab[buf][(256 + wv * 64) * 8]);
    }
  };

  if (PROJ) {
    int r = tid >> 4, s0 = tid & 15;
#pragma unroll
    for (int i = 0; i < 4; ++i) {
      int s = s0 + i * 16;
      unsigned short u[8] = {0, 0, 0, 0, 0, 0, 0, 0};
      if (r < 8) {
        const float* wp = wout + (size_t)r * 512 + s * 8;
        float4 f0 = *(const float4*)wp;
        float4 f1 = *(const float4*)(wp + 4);
        u[0] = f2bf(f0.x); u[1] = f2bf(f0.y); u[2] = f2bf(f0.z); u[3] = f2bf(f0.w);
        u[4] = f2bf(f1.x); u[5] = f2bf(f1.y); u[6] = f2bf(f1.z); u[7] = f2bf(f1.w);
      }
      int off = r * 512 + (s >> 3) * 64 + (((s & 7) ^ (r & 7)) * 8);
      *(bf16x8*)&wo_lds[off] = *(bf16x8*)u;
    }
  }

  f32x4 acc[4][2];
  if (GATES) {
#pragma unroll
    for (int g = 0; g < 4; ++g) {
      float bv = bias[g * HID + j0 + nh * 16 + cl];
      f32x4 v = {bv, bv, bv, bv};
      acc[g][0] = v; acc[g][1] = v;
    }
  }
  f32x4 accp0 = {0, 0, 0, 0}, accp1 = {0, 0, 0, 0};
  if (PROJ) {
    float bo = (cl < 8) ? bout[cl] : 0.0f;
    f32x4 v = {bo, bo, bo, bo};
    accp0 = v; accp1 = v;
  }

  const size_t cbase = ((size_t)bid * 256 + tid) * 8;
  f32x4 c0 = {0, 0, 0, 0}, c1 = {0, 0, 0, 0};
  if (GATES && t > 0) { c0 = *(const f32x4*)&cst[cbase]; c1 = *(const f32x4*)&cst[cbase + 4]; }

  auto mfma_block = [&](int bu, int kkv) {
    const unsigned short* Al = Ab[bu];
    const unsigned short* Bl = Bb[bu];
#pragma unroll
    for (int ks = 0; ks < 2; ++ks) {
      const int sx = ((ks * 4 + q8) ^ (cl & 7)) * 8;
      bf16x8 af0 = *(const bf16x8*)&Al[(mq * 32 + cl) * 64 + sx];
      bf16x8 af1 = *(const bf16x8*)&Al[(mq * 32 + 16 + cl) * 64 + sx];
      if (GATES) {
#pragma unroll
        for (int g = 0; g < 4; ++g) {
          bf16x8 bf = *(const bf16x8*)&Bl[(g * 32 + nh * 16 + cl) * 64 + sx];
          acc[g][0] = __builtin_amdgcn_mfma_f32_16x16x32_bf16(af0, bf, acc[g][0], 0, 0, 0);
          acc[g][1] = __builtin_amdgcn_mfma_f32_16x16x32_bf16(af1, bf, acc[g][1], 0, 0, 0);
        }
      }
      if (PROJ && nh == 0 && kkv < 8) {
        bf16x8 wf = *(const bf16x8*)&wo_lds[cl * 512 + kkv * 64 + sx];
        accp0 = __builtin_amdgcn_mfma_f32_16x16x32_bf16(af0, wf, accp0, 0, 0, 0);
        accp1 = __builtin_amdgcn_mfma_f32_16x16x32_bf16(af1, wf, accp1, 0, 0, 0);
      }
    }
  };

  if (GATES && t == 0) {
    do_stage(0, 8);
    asm volatile("s_waitcnt vmcnt(0) lgkmcnt(0)" ::: "memory");
    __builtin_amdgcn_s_barrier();
    mfma_block(0, 8);
  } else {
    do_stage(0, 0);
    do_stage(1, 1);
    if (GATES) asm volatile("s_waitcnt vmcnt(6) lgkmcnt(0)" ::: "memory");
    else       asm volatile("s_waitcnt vmcnt(2) lgkmcnt(0)" ::: "memory");
    __builtin_amdgcn_s_barrier();
    const int kkEnd = GATES ? 8 : 7;
    for (int kk = 0;; ++kk) {
      mfma_block(kk & 1, kk);
      if (kk == kkEnd) break;
      asm volatile("" ::: "memory");
      __builtin_amdgcn_s_barrier();
      if (kk + 2 <= kkEnd) {
        do_stage(kk & 1, kk + 2);
        if (GATES) asm volatile("s_waitcnt vmcnt(6)" ::: "memory");
        else       asm volatile("s_waitcnt vmcnt(2)" ::: "memory");
      } else {
        asm volatile("s_waitcnt vmcnt(0)" ::: "memory");
      }
      asm volatile("" ::: "memory");
      __builtin_amdgcn_s_barrier();
    }
  }

  if (PROJ && nh == 0 && cl < 8) {
    const int tt = t - 1;
#pragma unroll
    for (int r = 0; r < 4; ++r) {
      int b = b0 + mq * 32 + q8 * 4 + r;
      out[((size_t)b * 64 + tt) * 8 + cl] = accp0[r];
      out[((size_t)(b + 16) * 64 + tt) * 8 + cl] = accp1[r];
    }
  }

  if (GATES) {
#pragma unroll
    for (int fm = 0; fm < 2; ++fm) {
      f32x4 cold = fm ? c1 : c0;
      f32x4 cn;
#pragma unroll
      for (int r = 0; r < 4; ++r) {
        float iv = sigm(acc[0][fm][r]);
        float fv = sigm(acc[1][fm][r]);
        float gv = tanh_f(acc[2][fm][r]);
        float ov = sigm(acc[3][fm][r]);
        float cv = fv * cold[r] + iv * gv;
        cn[r] = cv;
        hO[(mq * 32 + fm * 16 + q8 * 4 + r) * 40 + nh * 16 + cl] = f2bf(ov * tanh_f(cv));
      }
      if (fm) c1 = cn; else c0 = cn;
    }
    *(f32x4*)&cst[cbase] = c0;
    *(f32x4*)&cst[cbase + 4] = c1;
    __syncthreads();
    int row = tid >> 2, sg4 = tid & 3;
    unsigned short tmp[8];
#pragma unroll
    for (int e = 0; e < 8; ++e) tmp[e] = hO[row * 40 + sg4 * 8 + e];
    *(int4*)&hnext[(size_t)(b0 + row) * HID + j0 + sg4 * 8] = *(int4*)tmp;
  }
}

extern "C" void kernel_launch(void* const* d_in, const int* in_sizes, int n_in,
                              void* d_out, int out_size, void* d_ws, size_t ws_size,
                              hipStream_t stream) {
  const float* z    = (const float*)d_in[0];
  const float* wih  = (const float*)d_in[1];
  const float* whh  = (const float*)d_in[2];
  const float* bih  = (const float*)d_in[3];
  const float* bhh  = (const float*)d_in[4];
  const float* wout = (const float*)d_in[5];
  const float* bout = (const float*)d_in[6];
  float* out = (float*)d_out;

  char* ws = (char*)d_ws;
  unsigned short* wcat = (unsigned short*)(ws);              // 2,359,296
  unsigned short* zbf  = (unsigned short*)(ws + 2359296);    //   262,144
  float* bias          = (float*)(ws + 2621440);             //     8,192
  unsigned short* h0   = (unsigned short*)(ws + 2629632);    // 2,097,152
  unsigned short* h1   = (unsigned short*)(ws + 4726784);    // 2,097,152
  int* flags           = (int*)(ws + 6823936);               //    65,536
  float* cst           = (float*)(ws + 6889472);             // 4,194,304 (fallback)

  k_prep<<<dim3(648), dim3(256), 0, stream>>>(z, wih, whh, bih, bhh, wcat, zbf, bias);
  k_zero<<<dim3(64), dim3(256), 0, stream>>>(flags);

  P pp;
  pp.wcat = wcat; pp.zbf = zbf; pp.bias = bias; pp.wout = wout; pp.bout = bout;
  pp.h0 = h0; pp.h1 = h1; pp.out = out; pp.flags = flags;

  hipFuncSetAttribute((const void*)k_persist,
                      hipFuncAttributeMaxDynamicSharedMemorySize, SMEM_SZ);
  void* args[] = {&pp};
  hipError_t e = hipLaunchCooperativeKernel((const void*)k_persist, dim3(256), dim3(512),
                                            args, SMEM_SZ, stream);
  if (e == hipSuccess) return;

  for (int t = 0; t < TSTEP; ++t) {
    const unsigned short* hp = (t & 1) ? h0 : h1;
    unsigned short* hn = (t & 1) ? h1 : h0;
    if (t == 0)
      k_stepF<1, 0><<<dim3(512), dim3(256), 0, stream>>>(hp, hn, wcat, zbf, wout, bias,
                                                         bout, cst, out, t);
    else
      k_stepF<1, 1><<<dim3(512), dim3(256), 0, stream>>>(hp, hn, wcat, zbf, wout, bias,
                                                         bout, cst, out, t);
  }
  k_stepF<0, 1><<<dim3(32), dim3(256), 0, stream>>>(h1, h0, wcat, zbf, wout, bias,
                                                    bout, cst, out, TSTEP);
}